// Round 2
// baseline (617.691 us; speedup 1.0000x reference)
//
#include <hip/hip_runtime.h>
#include <cstdint>

#define N_NODES 100000
#define N_EDGES 1600000

// ---------------- preprocessing ----------------

__global__ __launch_bounds__(256) void k_init(float* deg, int* cnt) {
    int i = blockIdx.x * 256 + threadIdx.x;
    if (i < N_NODES) { deg[i] = 1.0f; cnt[i] = 0; }
}

__global__ __launch_bounds__(256) void k_edge1(const int* __restrict__ ei,
                                               const float* __restrict__ ea,
                                               float* deg, int* cnt) {
    int e = blockIdx.x * 256 + threadIdx.x;
    if (e >= N_EDGES) return;
    int d = ei[N_EDGES + e];
    float t = ea[e] * (1.0f / 200.0f);
    float w = __expf(-t * t);
    atomicAdd(&deg[d], w);
    atomicAdd(&cnt[d], 1);
}

__global__ __launch_bounds__(256) void k_dinv(float* deg) {
    int i = blockIdx.x * 256 + threadIdx.x;
    if (i < N_NODES) deg[i] = rsqrtf(deg[i]);
}

// exclusive scan: per-block (256) scan
__global__ __launch_bounds__(256) void k_scanA(const int* __restrict__ cnt,
                                               int* rowptr, int* bsums) {
    __shared__ int tmp[256];
    int t = threadIdx.x;
    int idx = blockIdx.x * 256 + t;
    int v = (idx < N_NODES) ? cnt[idx] : 0;
    tmp[t] = v;
    __syncthreads();
    for (int off = 1; off < 256; off <<= 1) {
        int u = (t >= off) ? tmp[t - off] : 0;
        __syncthreads();
        tmp[t] += u;
        __syncthreads();
    }
    if (idx < N_NODES) rowptr[idx] = tmp[t] - v;   // exclusive
    if (t == 255) bsums[blockIdx.x] = tmp[255];
}

__global__ __launch_bounds__(512) void k_scanB(int* bsums, int nb) {
    __shared__ int tmp[512];
    int t = threadIdx.x;
    int v = (t < nb) ? bsums[t] : 0;
    tmp[t] = v;
    __syncthreads();
    for (int off = 1; off < 512; off <<= 1) {
        int u = (t >= off) ? tmp[t - off] : 0;
        __syncthreads();
        tmp[t] += u;
        __syncthreads();
    }
    if (t < nb) bsums[t] = tmp[t] - v;             // exclusive
}

__global__ __launch_bounds__(256) void k_scanC(int* rowptr, int* cursor,
                                               const int* __restrict__ bsums) {
    int i = blockIdx.x * 256 + threadIdx.x;
    if (i < N_NODES) {
        int r = rowptr[i] + bsums[i >> 8];
        rowptr[i] = r;
        cursor[i] = r;
    } else if (i == N_NODES) {
        rowptr[N_NODES] = N_EDGES;
    }
}

__global__ __launch_bounds__(256) void k_fill(const int* __restrict__ ei,
                                              const float* __restrict__ ea,
                                              const float* __restrict__ dinv,
                                              int* cursor, int2* csr) {
    int e = blockIdx.x * 256 + threadIdx.x;
    if (e >= N_EDGES) return;
    int s = ei[e];
    int d = ei[N_EDGES + e];
    float t = ea[e] * (1.0f / 200.0f);
    float w = __expf(-t * t);
    float nrm = dinv[s] * w * dinv[d];
    int pos = atomicAdd(&cursor[d], 1);
    csr[pos] = make_int2(s, __float_as_int(nrm));
}

// ---------------- dense compute ----------------

// Y[N,64] = X[N,64] @ W[64,64], fp32 vector-ALU tiled GEMM (no fp32 MFMA on CDNA4)
__global__ __launch_bounds__(256) void k_gemm64(const float* __restrict__ X,
                                                const float* __restrict__ W,
                                                float* __restrict__ Y) {
    __shared__ float sX[64][65];
    __shared__ float sW[64][65];
    int t = threadIdx.x;
    int rb = blockIdx.x * 64;
#pragma unroll
    for (int i = 0; i < 16; ++i) {
        int idx = t + i * 256;
        int r = idx >> 6, c = idx & 63;
        sW[r][c] = W[idx];
        int gr = rb + r;
        sX[r][c] = (gr < N_NODES) ? X[(size_t)gr * 64 + c] : 0.0f;
    }
    __syncthreads();
    int tr = (t >> 4) * 4;
    int tc = (t & 15) * 4;
    float acc[4][4] = {{0.f}};
#pragma unroll 8
    for (int k = 0; k < 64; ++k) {
        float xv[4], wv[4];
#pragma unroll
        for (int i = 0; i < 4; ++i) xv[i] = sX[tr + i][k];
#pragma unroll
        for (int j = 0; j < 4; ++j) wv[j] = sW[k][tc + j];
#pragma unroll
        for (int i = 0; i < 4; ++i)
#pragma unroll
            for (int j = 0; j < 4; ++j) acc[i][j] = fmaf(xv[i], wv[j], acc[i][j]);
    }
#pragma unroll
    for (int i = 0; i < 4; ++i) {
        int gr = rb + tr + i;
        if (gr < N_NODES) {
            float4 v = make_float4(acc[i][0], acc[i][1], acc[i][2], acc[i][3]);
            *reinterpret_cast<float4*>(&Y[(size_t)gr * 64 + tc]) = v;
        }
    }
}

// one wave per node: OUT[i,f] = relu?( sum_e w_e*XW[src_e,f] + dinv[i]^2*XW[i,f] + bias[f] )
__global__ __launch_bounds__(256) void k_agg64(const float* __restrict__ XW,
                                               const int2* __restrict__ csr,
                                               const int* __restrict__ rowptr,
                                               const float* __restrict__ dinv,
                                               const float* __restrict__ bias,
                                               float* __restrict__ OUT, int relu) {
    int wid = (blockIdx.x * 256 + threadIdx.x) >> 6;
    int f = threadIdx.x & 63;
    if (wid >= N_NODES) return;
    float di = dinv[wid];
    float acc = di * di * XW[(size_t)wid * 64 + f];
    int beg = rowptr[wid], end = rowptr[wid + 1];
    for (int e = beg; e < end; ++e) {
        int2 cw = csr[e];
        acc = fmaf(__int_as_float(cw.y), XW[(size_t)cw.x * 64 + f], acc);
    }
    acc += bias[f];
    if (relu) acc = fmaxf(acc, 0.0f);
    OUT[(size_t)wid * 64 + f] = acc;
}

// xw3[i] = dot(H[i,:], W3)  (wave per node, shuffle reduce)
__global__ __launch_bounds__(256) void k_gemv64(const float* __restrict__ H,
                                                const float* __restrict__ W3,
                                                float* __restrict__ out) {
    int wid = (blockIdx.x * 256 + threadIdx.x) >> 6;
    int f = threadIdx.x & 63;
    if (wid >= N_NODES) return;
    float v = H[(size_t)wid * 64 + f] * W3[f];
#pragma unroll
    for (int off = 32; off > 0; off >>= 1) v += __shfl_down(v, off, 64);
    if (f == 0) out[wid] = v;
}

// out[i] = b3 + dinv[i]^2*xw3[i] + sum_e w_e*xw3[src_e]
__global__ __launch_bounds__(256) void k_agg_scalar(const float* __restrict__ xw3,
                                                    const int2* __restrict__ csr,
                                                    const int* __restrict__ rowptr,
                                                    const float* __restrict__ dinv,
                                                    const float* __restrict__ b3,
                                                    float* __restrict__ out) {
    int i = blockIdx.x * 256 + threadIdx.x;
    if (i >= N_NODES) return;
    float di = dinv[i];
    float acc = di * di * xw3[i];
    int beg = rowptr[i], end = rowptr[i + 1];
    for (int e = beg; e < end; ++e) {
        int2 cw = csr[e];
        acc = fmaf(__int_as_float(cw.y), xw3[cw.x], acc);
    }
    out[i] = acc + b3[0];
}

// ---------------- launch ----------------

extern "C" void kernel_launch(void* const* d_in, const int* in_sizes, int n_in,
                              void* d_out, int out_size, void* d_ws, size_t ws_size,
                              hipStream_t stream) {
    const float* x  = (const float*)d_in[0];
    const int*   ei = (const int*)d_in[1];     // harness delivers integer inputs as int32
    const float* ea = (const float*)d_in[2];
    const float* W1 = (const float*)d_in[3];
    const float* b1 = (const float*)d_in[4];
    const float* W2 = (const float*)d_in[5];
    const float* b2 = (const float*)d_in[6];
    const float* W3 = (const float*)d_in[7];
    const float* b3 = (const float*)d_in[8];
    float* out = (float*)d_out;

    char* ws = (char*)d_ws;
    size_t off = 0;
    auto alloc = [&](size_t bytes) -> void* {
        void* p = ws + off;
        off = (off + bytes + 255) & ~(size_t)255;
        return p;
    };
    float* deg    = (float*)alloc((size_t)N_NODES * 4);        // becomes dinv in place
    int*   cnt    = (int*)  alloc((size_t)N_NODES * 4);        // reused as cursor
    int*   rowptr = (int*)  alloc((size_t)(N_NODES + 1) * 4);
    int*   bsums  = (int*)  alloc(512 * 4);
    int2*  csr    = (int2*) alloc((size_t)N_EDGES * 8);
    float* bufA   = (float*)alloc((size_t)N_NODES * 64 * 4);   // tail reused as xw3
    float* bufB   = (float*)alloc((size_t)N_NODES * 64 * 4);
    int*   cursor = cnt;                                       // cnt dead after scanA
    float* xw3    = bufA;                                      // bufA dead after gemv (layer 3)

    const int nbN = (N_NODES + 255) / 256;   // 391
    const int nbE = (N_EDGES + 255) / 256;   // 6250
    const int nbG = (N_NODES + 63) / 64;     // 1563 gemm blocks
    const int nbW = N_NODES / 4;             // 25000 (4 waves/block, 1 wave/node)

    k_init<<<nbN, 256, 0, stream>>>(deg, cnt);
    k_edge1<<<nbE, 256, 0, stream>>>(ei, ea, deg, cnt);
    k_dinv<<<nbN, 256, 0, stream>>>(deg);
    k_scanA<<<nbN, 256, 0, stream>>>(cnt, rowptr, bsums);
    k_scanB<<<1, 512, 0, stream>>>(bsums, nbN);
    k_scanC<<<nbN, 256, 0, stream>>>(rowptr, cursor, bsums);
    k_fill<<<nbE, 256, 0, stream>>>(ei, ea, deg, cursor, csr);

    // layer 1
    k_gemm64<<<nbG, 256, 0, stream>>>(x, W1, bufA);
    k_agg64<<<nbW, 256, 0, stream>>>(bufA, csr, rowptr, deg, b1, bufB, 1);
    // layer 2
    k_gemm64<<<nbG, 256, 0, stream>>>(bufB, W2, bufA);
    k_agg64<<<nbW, 256, 0, stream>>>(bufA, csr, rowptr, deg, b2, bufB, 1);
    // layer 3
    k_gemv64<<<nbW, 256, 0, stream>>>(bufB, W3, xw3);
    k_agg_scalar<<<nbN, 256, 0, stream>>>(xw3, csr, rowptr, deg, b3, out);
}

// Round 3
// 473.202 us; speedup vs baseline: 1.3053x; 1.3053x over previous
//
#include <hip/hip_runtime.h>
#include <cstdint>

#define N_NODES 100000
#define N_EDGES 1600000

// ---------------- preprocessing ----------------

__global__ __launch_bounds__(256) void k_init(float* deg, int* cnt) {
    int i = blockIdx.x * 256 + threadIdx.x;
    if (i < N_NODES) { deg[i] = 1.0f; cnt[i] = 0; }
}

__global__ __launch_bounds__(256) void k_edge1(const int* __restrict__ ei,
                                               const float* __restrict__ ea,
                                               float* deg, int* cnt) {
    int e = blockIdx.x * 256 + threadIdx.x;
    if (e >= N_EDGES) return;
    int d = ei[N_EDGES + e];
    float t = ea[e] * (1.0f / 200.0f);
    float w = __expf(-t * t);
    atomicAdd(&deg[d], w);
    atomicAdd(&cnt[d], 1);
}

// per-block exclusive scan of cnt; also converts deg -> rsqrt(deg) in place
__global__ __launch_bounds__(256) void k_scanA(const int* __restrict__ cnt,
                                               int* rowptr, int* bsums, float* deg) {
    __shared__ int tmp[256];
    int t = threadIdx.x;
    int idx = blockIdx.x * 256 + t;
    if (idx < N_NODES) deg[idx] = rsqrtf(deg[idx]);
    int v = (idx < N_NODES) ? cnt[idx] : 0;
    tmp[t] = v;
    __syncthreads();
    for (int off = 1; off < 256; off <<= 1) {
        int u = (t >= off) ? tmp[t - off] : 0;
        __syncthreads();
        tmp[t] += u;
        __syncthreads();
    }
    if (idx < N_NODES) rowptr[idx] = tmp[t] - v;   // exclusive
    if (t == 255) bsums[blockIdx.x] = tmp[255];
}

__global__ __launch_bounds__(512) void k_scanB(int* bsums, int nb) {
    __shared__ int tmp[512];
    int t = threadIdx.x;
    int v = (t < nb) ? bsums[t] : 0;
    tmp[t] = v;
    __syncthreads();
    for (int off = 1; off < 512; off <<= 1) {
        int u = (t >= off) ? tmp[t - off] : 0;
        __syncthreads();
        tmp[t] += u;
        __syncthreads();
    }
    if (t < nb) bsums[t] = tmp[t] - v;             // exclusive
}

__global__ __launch_bounds__(256) void k_scanC(int* rowptr, int* cursor,
                                               const int* __restrict__ bsums) {
    int i = blockIdx.x * 256 + threadIdx.x;
    if (i < N_NODES) {
        int r = rowptr[i] + bsums[i >> 8];
        rowptr[i] = r;
        cursor[i] = r;
    } else if (i == N_NODES) {
        rowptr[N_NODES] = N_EDGES;
    }
}

__global__ __launch_bounds__(256) void k_fill(const int* __restrict__ ei,
                                              const float* __restrict__ ea,
                                              const float* __restrict__ dinv,
                                              int* cursor, int2* csr) {
    int e = blockIdx.x * 256 + threadIdx.x;
    if (e >= N_EDGES) return;
    int s = ei[e];
    int d = ei[N_EDGES + e];
    float t = ea[e] * (1.0f / 200.0f);
    float w = __expf(-t * t);
    float nrm = dinv[s] * w * dinv[d];
    int pos = atomicAdd(&cursor[d], 1);
    csr[pos] = make_int2(s, __float_as_int(nrm));
}

// ---------------- dense compute ----------------

// Y[N,64] = X[N,64] @ W[64,64], fp32 vector-ALU tiled GEMM (no fp32 MFMA on CDNA4)
__global__ __launch_bounds__(256) void k_gemm64(const float* __restrict__ X,
                                                const float* __restrict__ W,
                                                float* __restrict__ Y) {
    __shared__ float sX[64][65];
    __shared__ float sW[64][65];
    int t = threadIdx.x;
    int rb = blockIdx.x * 64;
#pragma unroll
    for (int i = 0; i < 16; ++i) {
        int idx = t + i * 256;
        int r = idx >> 6, c = idx & 63;
        sW[r][c] = W[idx];
        int gr = rb + r;
        sX[r][c] = (gr < N_NODES) ? X[(size_t)gr * 64 + c] : 0.0f;
    }
    __syncthreads();
    int tr = (t >> 4) * 4;
    int tc = (t & 15) * 4;
    float acc[4][4] = {{0.f}};
#pragma unroll 8
    for (int k = 0; k < 64; ++k) {
        float xv[4], wv[4];
#pragma unroll
        for (int i = 0; i < 4; ++i) xv[i] = sX[tr + i][k];
#pragma unroll
        for (int j = 0; j < 4; ++j) wv[j] = sW[k][tc + j];
#pragma unroll
        for (int i = 0; i < 4; ++i)
#pragma unroll
            for (int j = 0; j < 4; ++j) acc[i][j] = fmaf(xv[i], wv[j], acc[i][j]);
    }
#pragma unroll
    for (int i = 0; i < 4; ++i) {
        int gr = rb + tr + i;
        if (gr < N_NODES) {
            float4 v = make_float4(acc[i][0], acc[i][1], acc[i][2], acc[i][3]);
            *reinterpret_cast<float4*>(&Y[(size_t)gr * 64 + tc]) = v;
        }
    }
}

// one wave per node, lane = feature. 8-wide MLP unroll on the edge gather.
// MODE 0: OUT[i,f] = relu(agg + bias)       (full row, [N,64])
// MODE 1: h = relu(agg + bias); OUT[i] = dot(h, W3)  (scalar, [N])
template <int MODE>
__global__ __launch_bounds__(256) void k_agg64(const float* __restrict__ XW,
                                               const int2* __restrict__ csr,
                                               const int* __restrict__ rowptr,
                                               const float* __restrict__ dinv,
                                               const float* __restrict__ bias,
                                               float* __restrict__ OUT,
                                               const float* __restrict__ W3) {
    int wid = (blockIdx.x * 256 + threadIdx.x) >> 6;
    int f = threadIdx.x & 63;
    if (wid >= N_NODES) return;
    float di = dinv[wid];
    float acc = di * di * XW[(size_t)wid * 64 + f];
    int beg = rowptr[wid], end = rowptr[wid + 1];
    float a[8] = {0.f, 0.f, 0.f, 0.f, 0.f, 0.f, 0.f, 0.f};
    for (int e = beg; e < end; e += 8) {
        int   idx[8];
        float w[8];
#pragma unroll
        for (int j = 0; j < 8; ++j) {
            int ee = e + j;
            int2 c = csr[ee < end ? ee : beg];          // always in-bounds
            idx[j] = c.x;
            w[j] = (ee < end) ? __int_as_float(c.y) : 0.0f;
        }
        float r[8];
#pragma unroll
        for (int j = 0; j < 8; ++j) r[j] = XW[(size_t)idx[j] * 64 + f];
#pragma unroll
        for (int j = 0; j < 8; ++j) a[j] = fmaf(w[j], r[j], a[j]);
    }
    acc += ((a[0] + a[1]) + (a[2] + a[3])) + ((a[4] + a[5]) + (a[6] + a[7]));
    acc += bias[f];
    acc = fmaxf(acc, 0.0f);
    if (MODE == 0) {
        OUT[(size_t)wid * 64 + f] = acc;
    } else {
        float v = acc * W3[f];
#pragma unroll
        for (int off = 32; off > 0; off >>= 1) v += __shfl_down(v, off, 64);
        if (f == 0) OUT[wid] = v;
    }
}

// out[i] = b3 + dinv[i]^2*xw3[i] + sum_e w_e*xw3[src_e]   (4-wide MLP unroll)
__global__ __launch_bounds__(256) void k_agg_scalar(const float* __restrict__ xw3,
                                                    const int2* __restrict__ csr,
                                                    const int* __restrict__ rowptr,
                                                    const float* __restrict__ dinv,
                                                    const float* __restrict__ b3,
                                                    float* __restrict__ out) {
    int i = blockIdx.x * 256 + threadIdx.x;
    if (i >= N_NODES) return;
    float di = dinv[i];
    float acc = di * di * xw3[i];
    int beg = rowptr[i], end = rowptr[i + 1];
    float a0 = 0.f, a1 = 0.f, a2 = 0.f, a3 = 0.f;
    for (int e = beg; e < end; e += 4) {
        int2 c0 = csr[e];
        int2 c1 = csr[e + 1 < end ? e + 1 : beg];
        int2 c2 = csr[e + 2 < end ? e + 2 : beg];
        int2 c3 = csr[e + 3 < end ? e + 3 : beg];
        float w1 = (e + 1 < end) ? __int_as_float(c1.y) : 0.0f;
        float w2 = (e + 2 < end) ? __int_as_float(c2.y) : 0.0f;
        float w3 = (e + 3 < end) ? __int_as_float(c3.y) : 0.0f;
        float r0 = xw3[c0.x], r1 = xw3[c1.x], r2 = xw3[c2.x], r3 = xw3[c3.x];
        a0 = fmaf(__int_as_float(c0.y), r0, a0);
        a1 = fmaf(w1, r1, a1);
        a2 = fmaf(w2, r2, a2);
        a3 = fmaf(w3, r3, a3);
    }
    out[i] = acc + (a0 + a1) + (a2 + a3) + b3[0];
}

// ---------------- launch ----------------

extern "C" void kernel_launch(void* const* d_in, const int* in_sizes, int n_in,
                              void* d_out, int out_size, void* d_ws, size_t ws_size,
                              hipStream_t stream) {
    const float* x  = (const float*)d_in[0];
    const int*   ei = (const int*)d_in[1];     // harness delivers integer inputs as int32
    const float* ea = (const float*)d_in[2];
    const float* W1 = (const float*)d_in[3];
    const float* b1 = (const float*)d_in[4];
    const float* W2 = (const float*)d_in[5];
    const float* b2 = (const float*)d_in[6];
    const float* W3 = (const float*)d_in[7];
    const float* b3 = (const float*)d_in[8];
    float* out = (float*)d_out;

    char* ws = (char*)d_ws;
    size_t off = 0;
    auto alloc = [&](size_t bytes) -> void* {
        void* p = ws + off;
        off = (off + bytes + 255) & ~(size_t)255;
        return p;
    };
    float* deg    = (float*)alloc((size_t)N_NODES * 4);        // becomes dinv in place
    int*   cnt    = (int*)  alloc((size_t)N_NODES * 4);        // reused as cursor
    int*   rowptr = (int*)  alloc((size_t)(N_NODES + 1) * 4);
    int*   bsums  = (int*)  alloc(512 * 4);
    float* xw3    = (float*)alloc((size_t)N_NODES * 4);        // compact, L2-resident
    int2*  csr    = (int2*) alloc((size_t)N_EDGES * 8);
    float* bufA   = (float*)alloc((size_t)N_NODES * 64 * 4);
    float* bufB   = (float*)alloc((size_t)N_NODES * 64 * 4);
    int*   cursor = cnt;                                       // cnt dead after scanA

    const int nbN = (N_NODES + 255) / 256;   // 391
    const int nbE = (N_EDGES + 255) / 256;   // 6250
    const int nbG = (N_NODES + 63) / 64;     // 1563 gemm blocks
    const int nbW = N_NODES / 4;             // 25000 (4 waves/block, 1 wave/node)

    k_init<<<nbN, 256, 0, stream>>>(deg, cnt);
    k_edge1<<<nbE, 256, 0, stream>>>(ei, ea, deg, cnt);
    k_scanA<<<nbN, 256, 0, stream>>>(cnt, rowptr, bsums, deg);  // also deg -> dinv
    k_scanB<<<1, 512, 0, stream>>>(bsums, nbN);
    k_scanC<<<nbN, 256, 0, stream>>>(rowptr, cursor, bsums);
    k_fill<<<nbE, 256, 0, stream>>>(ei, ea, deg, cursor, csr);

    // layer 1
    k_gemm64<<<nbG, 256, 0, stream>>>(x, W1, bufA);
    k_agg64<0><<<nbW, 256, 0, stream>>>(bufA, csr, rowptr, deg, b1, bufB, nullptr);
    // layer 2 (+ fused layer-3 GEMV: h2 row stays in registers)
    k_gemm64<<<nbG, 256, 0, stream>>>(bufB, W2, bufA);
    k_agg64<1><<<nbW, 256, 0, stream>>>(bufA, csr, rowptr, deg, b2, xw3, W3);
    // layer 3
    k_agg_scalar<<<nbN, 256, 0, stream>>>(xw3, csr, rowptr, deg, b3, out);
}

// Round 4
// 446.329 us; speedup vs baseline: 1.3839x; 1.0602x over previous
//
#include <hip/hip_runtime.h>
#include <cstdint>

#define N_NODES 100000
#define N_EDGES 1600000

// ---------------- preprocessing ----------------

__global__ __launch_bounds__(256) void k_init(int* cnt) {
    int i = blockIdx.x * 256 + threadIdx.x;
    if (i < N_NODES) cnt[i] = 0;
}

// histogram of dst only (int atomics; float deg computed later without atomics)
__global__ __launch_bounds__(256) void k_hist(const int* __restrict__ dst, int* cnt) {
    int e0 = (blockIdx.x * 256 + threadIdx.x) * 4;
    if (e0 + 3 < N_EDGES) {
        int4 d = *reinterpret_cast<const int4*>(&dst[e0]);
        atomicAdd(&cnt[d.x], 1);
        atomicAdd(&cnt[d.y], 1);
        atomicAdd(&cnt[d.z], 1);
        atomicAdd(&cnt[d.w], 1);
    } else {
        for (int e = e0; e < N_EDGES; ++e) atomicAdd(&cnt[dst[e]], 1);
    }
}

// per-block exclusive scan of cnt
__global__ __launch_bounds__(256) void k_scanA(const int* __restrict__ cnt,
                                               int* rowptr, int* bsums) {
    __shared__ int tmp[256];
    int t = threadIdx.x;
    int idx = blockIdx.x * 256 + t;
    int v = (idx < N_NODES) ? cnt[idx] : 0;
    tmp[t] = v;
    __syncthreads();
    for (int off = 1; off < 256; off <<= 1) {
        int u = (t >= off) ? tmp[t - off] : 0;
        __syncthreads();
        tmp[t] += u;
        __syncthreads();
    }
    if (idx < N_NODES) rowptr[idx] = tmp[t] - v;   // exclusive
    if (t == 255) bsums[blockIdx.x] = tmp[255];
}

__global__ __launch_bounds__(512) void k_scanB(int* bsums, int nb) {
    __shared__ int tmp[512];
    int t = threadIdx.x;
    int v = (t < nb) ? bsums[t] : 0;
    tmp[t] = v;
    __syncthreads();
    for (int off = 1; off < 512; off <<= 1) {
        int u = (t >= off) ? tmp[t - off] : 0;
        __syncthreads();
        tmp[t] += u;
        __syncthreads();
    }
    if (t < nb) bsums[t] = tmp[t] - v;             // exclusive
}

__global__ __launch_bounds__(256) void k_scanC(int* rowptr, int* cursor,
                                               const int* __restrict__ bsums) {
    int i = blockIdx.x * 256 + threadIdx.x;
    if (i < N_NODES) {
        int r = rowptr[i] + bsums[i >> 8];
        rowptr[i] = r;
        cursor[i] = r;
    } else if (i == N_NODES) {
        rowptr[N_NODES] = N_EDGES;
    }
}

// scatter edges into CSR slots; store (src, w) — dinv folded in later
__global__ __launch_bounds__(256) void k_fill(const int* __restrict__ ei,
                                              const float* __restrict__ ea,
                                              int* cursor, int2* csr) {
    int e = blockIdx.x * 256 + threadIdx.x;
    if (e >= N_EDGES) return;
    int s = ei[e];
    int d = ei[N_EDGES + e];
    float t = ea[e] * (1.0f / 200.0f);
    float w = __expf(-t * t);
    int pos = atomicAdd(&cursor[d], 1);
    csr[pos] = make_int2(s, __float_as_int(w));
}

// deg[i] = 1 + sum of row weights (gather, no atomics); store dinv = rsqrt(deg)
__global__ __launch_bounds__(256) void k_deg(const int2* __restrict__ csr,
                                             const int* __restrict__ rowptr,
                                             float* __restrict__ dinv) {
    int i = blockIdx.x * 256 + threadIdx.x;
    if (i >= N_NODES) return;
    int beg = rowptr[i], end = rowptr[i + 1];
    float a0 = 0.f, a1 = 0.f, a2 = 0.f, a3 = 0.f;
    for (int e = beg; e < end; e += 4) {
        int2 c0 = csr[e];
        int2 c1 = csr[e + 1 < end ? e + 1 : beg];
        int2 c2 = csr[e + 2 < end ? e + 2 : beg];
        int2 c3 = csr[e + 3 < end ? e + 3 : beg];
        a0 += __int_as_float(c0.y);
        a1 += (e + 1 < end) ? __int_as_float(c1.y) : 0.0f;
        a2 += (e + 2 < end) ? __int_as_float(c2.y) : 0.0f;
        a3 += (e + 3 < end) ? __int_as_float(c3.y) : 0.0f;
    }
    dinv[i] = rsqrtf(1.0f + (a0 + a1) + (a2 + a3));
}

// csr[e].w *= dinv[src]  (streaming rewrite; dinv[dst] factored out algebraically)
__global__ __launch_bounds__(256) void k_fold(int2* csr, const float* __restrict__ dinv) {
    int e = blockIdx.x * 256 + threadIdx.x;
    if (e >= N_EDGES) return;
    int2 c = csr[e];
    c.y = __float_as_int(__int_as_float(c.y) * dinv[c.x]);
    csr[e] = c;
}

// ---------------- dense compute ----------------

// Y[N,64] = X[N,64] @ W[64,64], fp32 vector-ALU tiled GEMM (no fp32 MFMA on CDNA4)
__global__ __launch_bounds__(256) void k_gemm64(const float* __restrict__ X,
                                                const float* __restrict__ W,
                                                float* __restrict__ Y) {
    __shared__ float sX[64][65];
    __shared__ float sW[64][65];
    int t = threadIdx.x;
    int rb = blockIdx.x * 64;
#pragma unroll
    for (int i = 0; i < 16; ++i) {
        int idx = t + i * 256;
        int r = idx >> 6, c = idx & 63;
        sW[r][c] = W[idx];
        int gr = rb + r;
        sX[r][c] = (gr < N_NODES) ? X[(size_t)gr * 64 + c] : 0.0f;
    }
    __syncthreads();
    int tr = (t >> 4) * 4;
    int tc = (t & 15) * 4;
    float acc[4][4] = {{0.f}};
#pragma unroll 8
    for (int k = 0; k < 64; ++k) {
        float xv[4], wv[4];
#pragma unroll
        for (int i = 0; i < 4; ++i) xv[i] = sX[tr + i][k];
#pragma unroll
        for (int j = 0; j < 4; ++j) wv[j] = sW[k][tc + j];
#pragma unroll
        for (int i = 0; i < 4; ++i)
#pragma unroll
            for (int j = 0; j < 4; ++j) acc[i][j] = fmaf(xv[i], wv[j], acc[i][j]);
    }
#pragma unroll
    for (int i = 0; i < 4; ++i) {
        int gr = rb + tr + i;
        if (gr < N_NODES) {
            float4 v = make_float4(acc[i][0], acc[i][1], acc[i][2], acc[i][3]);
            *reinterpret_cast<float4*>(&Y[(size_t)gr * 64 + tc]) = v;
        }
    }
}

// one wave per node, lane = feature. 8-wide MLP unroll on the edge gather.
// csr.y already holds w*dinv[src]; dinv[dst] applied at the end.
// MODE 0: OUT[i,f] = relu(agg + bias)       (full row, [N,64])
// MODE 1: h = relu(agg + bias); OUT[i] = dot(h, W3)  (scalar, [N])
template <int MODE>
__global__ __launch_bounds__(256) void k_agg64(const float* __restrict__ XW,
                                               const int2* __restrict__ csr,
                                               const int* __restrict__ rowptr,
                                               const float* __restrict__ dinv,
                                               const float* __restrict__ bias,
                                               float* __restrict__ OUT,
                                               const float* __restrict__ W3) {
    int wid = (blockIdx.x * 256 + threadIdx.x) >> 6;
    int f = threadIdx.x & 63;
    if (wid >= N_NODES) return;
    float di = dinv[wid];
    float self = XW[(size_t)wid * 64 + f];
    int beg = rowptr[wid], end = rowptr[wid + 1];
    float a[8] = {0.f, 0.f, 0.f, 0.f, 0.f, 0.f, 0.f, 0.f};
    for (int e = beg; e < end; e += 8) {
        int   idx[8];
        float w[8];
#pragma unroll
        for (int j = 0; j < 8; ++j) {
            int ee = e + j;
            int2 c = csr[ee < end ? ee : beg];          // always in-bounds
            idx[j] = c.x;
            w[j] = (ee < end) ? __int_as_float(c.y) : 0.0f;
        }
        float r[8];
#pragma unroll
        for (int j = 0; j < 8; ++j) r[j] = XW[(size_t)idx[j] * 64 + f];
#pragma unroll
        for (int j = 0; j < 8; ++j) a[j] = fmaf(w[j], r[j], a[j]);
    }
    float esum = ((a[0] + a[1]) + (a[2] + a[3])) + ((a[4] + a[5]) + (a[6] + a[7]));
    float acc = di * (di * self + esum) + bias[f];
    acc = fmaxf(acc, 0.0f);
    if (MODE == 0) {
        OUT[(size_t)wid * 64 + f] = acc;
    } else {
        float v = acc * W3[f];
#pragma unroll
        for (int off = 32; off > 0; off >>= 1) v += __shfl_down(v, off, 64);
        if (f == 0) OUT[wid] = v;
    }
}

// out[i] = b3 + di*(di*xw3[i] + sum_e v_e*xw3[src_e])   (4-wide MLP unroll)
__global__ __launch_bounds__(256) void k_agg_scalar(const float* __restrict__ xw3,
                                                    const int2* __restrict__ csr,
                                                    const int* __restrict__ rowptr,
                                                    const float* __restrict__ dinv,
                                                    const float* __restrict__ b3,
                                                    float* __restrict__ out) {
    int i = blockIdx.x * 256 + threadIdx.x;
    if (i >= N_NODES) return;
    float di = dinv[i];
    int beg = rowptr[i], end = rowptr[i + 1];
    float a0 = 0.f, a1 = 0.f, a2 = 0.f, a3 = 0.f;
    for (int e = beg; e < end; e += 4) {
        int2 c0 = csr[e];
        int2 c1 = csr[e + 1 < end ? e + 1 : beg];
        int2 c2 = csr[e + 2 < end ? e + 2 : beg];
        int2 c3 = csr[e + 3 < end ? e + 3 : beg];
        float w1 = (e + 1 < end) ? __int_as_float(c1.y) : 0.0f;
        float w2 = (e + 2 < end) ? __int_as_float(c2.y) : 0.0f;
        float w3 = (e + 3 < end) ? __int_as_float(c3.y) : 0.0f;
        a0 = fmaf(__int_as_float(c0.y), xw3[c0.x], a0);
        a1 = fmaf(w1, xw3[c1.x], a1);
        a2 = fmaf(w2, xw3[c2.x], a2);
        a3 = fmaf(w3, xw3[c3.x], a3);
    }
    out[i] = di * (di * xw3[i] + (a0 + a1) + (a2 + a3)) + b3[0];
}

// ---------------- launch ----------------

extern "C" void kernel_launch(void* const* d_in, const int* in_sizes, int n_in,
                              void* d_out, int out_size, void* d_ws, size_t ws_size,
                              hipStream_t stream) {
    const float* x  = (const float*)d_in[0];
    const int*   ei = (const int*)d_in[1];     // harness delivers integer inputs as int32
    const float* ea = (const float*)d_in[2];
    const float* W1 = (const float*)d_in[3];
    const float* b1 = (const float*)d_in[4];
    const float* W2 = (const float*)d_in[5];
    const float* b2 = (const float*)d_in[6];
    const float* W3 = (const float*)d_in[7];
    const float* b3 = (const float*)d_in[8];
    float* out = (float*)d_out;

    char* ws = (char*)d_ws;
    size_t off = 0;
    auto alloc = [&](size_t bytes) -> void* {
        void* p = ws + off;
        off = (off + bytes + 255) & ~(size_t)255;
        return p;
    };
    float* dinv   = (float*)alloc((size_t)N_NODES * 4);
    int*   cnt    = (int*)  alloc((size_t)N_NODES * 4);        // reused as cursor
    int*   rowptr = (int*)  alloc((size_t)(N_NODES + 1) * 4);
    int*   bsums  = (int*)  alloc(512 * 4);
    float* xw3    = (float*)alloc((size_t)N_NODES * 4);        // compact, L2-resident
    int2*  csr    = (int2*) alloc((size_t)N_EDGES * 8);
    float* bufA   = (float*)alloc((size_t)N_NODES * 64 * 4);
    float* bufB   = (float*)alloc((size_t)N_NODES * 64 * 4);
    int*   cursor = cnt;                                       // cnt dead after scanA

    const int nbN = (N_NODES + 255) / 256;   // 391
    const int nbE = (N_EDGES + 255) / 256;   // 6250
    const int nbH = (N_EDGES / 4 + 255) / 256; // 1563 (4 edges/thread)
    const int nbG = (N_NODES + 63) / 64;     // 1563 gemm blocks
    const int nbW = N_NODES / 4;             // 25000 (4 waves/block, 1 wave/node)

    k_init<<<nbN, 256, 0, stream>>>(cnt);
    k_hist<<<nbH, 256, 0, stream>>>(ei + N_EDGES, cnt);
    k_scanA<<<nbN, 256, 0, stream>>>(cnt, rowptr, bsums);
    k_scanB<<<1, 512, 0, stream>>>(bsums, nbN);
    k_scanC<<<nbN, 256, 0, stream>>>(rowptr, cursor, bsums);
    k_fill<<<nbE, 256, 0, stream>>>(ei, ea, cursor, csr);
    k_deg<<<nbN, 256, 0, stream>>>(csr, rowptr, dinv);
    k_fold<<<nbE, 256, 0, stream>>>(csr, dinv);

    // layer 1
    k_gemm64<<<nbG, 256, 0, stream>>>(x, W1, bufA);
    k_agg64<0><<<nbW, 256, 0, stream>>>(bufA, csr, rowptr, dinv, b1, bufB, nullptr);
    // layer 2 (+ fused layer-3 GEMV: h2 row stays in registers)
    k_gemm64<<<nbG, 256, 0, stream>>>(bufB, W2, bufA);
    k_agg64<1><<<nbW, 256, 0, stream>>>(bufA, csr, rowptr, dinv, b2, xw3, W3);
    // layer 3
    k_agg_scalar<<<nbN, 256, 0, stream>>>(xw3, csr, rowptr, dinv, b3, out);
}

// Round 5
// 347.299 us; speedup vs baseline: 1.7786x; 1.2851x over previous
//
#include <hip/hip_runtime.h>
#include <cstdint>

#define N_NODES 100000
#define N_EDGES 1600000
#define NBH 1563   // hist blocks (4 edges/thread, 256 threads)
#define NBG 1563   // gemm blocks (64 rows/block)

// ---------------- preprocessing ----------------

__global__ __launch_bounds__(256) void k_init(int* cnt) {
    int i = blockIdx.x * 256 + threadIdx.x;
    if (i < N_NODES) cnt[i] = 0;
}

// Fused dispatch: blocks [0,NBH) histogram dst AND record per-edge rank
// (the atomic's return value); blocks [NBH,NBH+NBG) do layer-1 GEMM —
// independent streaming work hidden under the atomic-rate-bound histogram.
__global__ __launch_bounds__(256) void k_histrank_gemm(const int* __restrict__ dst,
                                                       int* cnt,
                                                       int* __restrict__ rank,
                                                       const float* __restrict__ X,
                                                       const float* __restrict__ W,
                                                       float* __restrict__ Y) {
    __shared__ float sX[64][65];
    __shared__ float sW[64][65];
    if (blockIdx.x < NBH) {
        int e0 = (blockIdx.x * 256 + threadIdx.x) * 4;
        if (e0 + 3 < N_EDGES) {
            int4 d = *reinterpret_cast<const int4*>(&dst[e0]);
            int4 r;
            r.x = atomicAdd(&cnt[d.x], 1);
            r.y = atomicAdd(&cnt[d.y], 1);
            r.z = atomicAdd(&cnt[d.z], 1);
            r.w = atomicAdd(&cnt[d.w], 1);
            *reinterpret_cast<int4*>(&rank[e0]) = r;
        } else {
            for (int e = e0; e < N_EDGES; ++e) rank[e] = atomicAdd(&cnt[dst[e]], 1);
        }
        return;
    }
    // ---- gemm1 part: Y[rb:rb+64,:] = X @ W ----
    int t = threadIdx.x;
    int rb = (blockIdx.x - NBH) * 64;
#pragma unroll
    for (int i = 0; i < 16; ++i) {
        int idx = t + i * 256;
        int r = idx >> 6, c = idx & 63;
        sW[r][c] = W[idx];
        int gr = rb + r;
        sX[r][c] = (gr < N_NODES) ? X[(size_t)gr * 64 + c] : 0.0f;
    }
    __syncthreads();
    int tr = (t >> 4) * 4;
    int tc = (t & 15) * 4;
    float acc[4][4] = {{0.f}};
#pragma unroll 8
    for (int k = 0; k < 64; ++k) {
        float xv[4], wv[4];
#pragma unroll
        for (int i = 0; i < 4; ++i) xv[i] = sX[tr + i][k];
#pragma unroll
        for (int j = 0; j < 4; ++j) wv[j] = sW[k][tc + j];
#pragma unroll
        for (int i = 0; i < 4; ++i)
#pragma unroll
            for (int j = 0; j < 4; ++j) acc[i][j] = fmaf(xv[i], wv[j], acc[i][j]);
    }
#pragma unroll
    for (int i = 0; i < 4; ++i) {
        int gr = rb + tr + i;
        if (gr < N_NODES) {
            float4 v = make_float4(acc[i][0], acc[i][1], acc[i][2], acc[i][3]);
            *reinterpret_cast<float4*>(&Y[(size_t)gr * 64 + tc]) = v;
        }
    }
}

// per-block exclusive scan of cnt
__global__ __launch_bounds__(256) void k_scanA(const int* __restrict__ cnt,
                                               int* rowptr, int* bsums) {
    __shared__ int tmp[256];
    int t = threadIdx.x;
    int idx = blockIdx.x * 256 + t;
    int v = (idx < N_NODES) ? cnt[idx] : 0;
    tmp[t] = v;
    __syncthreads();
    for (int off = 1; off < 256; off <<= 1) {
        int u = (t >= off) ? tmp[t - off] : 0;
        __syncthreads();
        tmp[t] += u;
        __syncthreads();
    }
    if (idx < N_NODES) rowptr[idx] = tmp[t] - v;   // exclusive
    if (t == 255) bsums[blockIdx.x] = tmp[255];
}

__global__ __launch_bounds__(512) void k_scanB(int* bsums, int nb) {
    __shared__ int tmp[512];
    int t = threadIdx.x;
    int v = (t < nb) ? bsums[t] : 0;
    tmp[t] = v;
    __syncthreads();
    for (int off = 1; off < 512; off <<= 1) {
        int u = (t >= off) ? tmp[t - off] : 0;
        __syncthreads();
        tmp[t] += u;
        __syncthreads();
    }
    if (t < nb) bsums[t] = tmp[t] - v;             // exclusive
}

__global__ __launch_bounds__(256) void k_scanC(int* rowptr, const int* __restrict__ bsums) {
    int i = blockIdx.x * 256 + threadIdx.x;
    if (i < N_NODES) {
        rowptr[i] += bsums[i >> 8];
    } else if (i == N_NODES) {
        rowptr[N_NODES] = N_EDGES;
    }
}

// scatter edges into CSR slots — NO atomics: pos = rowptr[dst] + rank[e]
__global__ __launch_bounds__(256) void k_fill(const int* __restrict__ ei,
                                              const float* __restrict__ ea,
                                              const int* __restrict__ rank,
                                              const int* __restrict__ rowptr,
                                              int2* __restrict__ csr) {
    int e = blockIdx.x * 256 + threadIdx.x;
    if (e >= N_EDGES) return;
    int s = ei[e];
    int d = ei[N_EDGES + e];
    float t = ea[e] * (1.0f / 200.0f);
    float w = __expf(-t * t);
    int pos = rowptr[d] + rank[e];
    csr[pos] = make_int2(s, __float_as_int(w));
}

// deg[i] = 1 + sum of row weights (gather, no atomics); store dinv = rsqrt(deg)
__global__ __launch_bounds__(256) void k_deg(const int2* __restrict__ csr,
                                             const int* __restrict__ rowptr,
                                             float* __restrict__ dinv) {
    int i = blockIdx.x * 256 + threadIdx.x;
    if (i >= N_NODES) return;
    int beg = rowptr[i], end = rowptr[i + 1];
    float a0 = 0.f, a1 = 0.f, a2 = 0.f, a3 = 0.f;
    for (int e = beg; e < end; e += 4) {
        int2 c0 = csr[e];
        int2 c1 = csr[e + 1 < end ? e + 1 : beg];
        int2 c2 = csr[e + 2 < end ? e + 2 : beg];
        int2 c3 = csr[e + 3 < end ? e + 3 : beg];
        a0 += __int_as_float(c0.y);
        a1 += (e + 1 < end) ? __int_as_float(c1.y) : 0.0f;
        a2 += (e + 2 < end) ? __int_as_float(c2.y) : 0.0f;
        a3 += (e + 3 < end) ? __int_as_float(c3.y) : 0.0f;
    }
    dinv[i] = rsqrtf(1.0f + (a0 + a1) + (a2 + a3));
}

// csr[e].w *= dinv[src]  (streaming rewrite; dinv[dst] factored out algebraically)
__global__ __launch_bounds__(256) void k_fold(int2* csr, const float* __restrict__ dinv) {
    int e = blockIdx.x * 256 + threadIdx.x;
    if (e >= N_EDGES) return;
    int2 c = csr[e];
    c.y = __float_as_int(__int_as_float(c.y) * dinv[c.x]);
    csr[e] = c;
}

// ---------------- dense compute ----------------

// Y[N,64] = X[N,64] @ W[64,64], fp32 vector-ALU tiled GEMM (no fp32 MFMA on CDNA4)
__global__ __launch_bounds__(256) void k_gemm64(const float* __restrict__ X,
                                                const float* __restrict__ W,
                                                float* __restrict__ Y) {
    __shared__ float sX[64][65];
    __shared__ float sW[64][65];
    int t = threadIdx.x;
    int rb = blockIdx.x * 64;
#pragma unroll
    for (int i = 0; i < 16; ++i) {
        int idx = t + i * 256;
        int r = idx >> 6, c = idx & 63;
        sW[r][c] = W[idx];
        int gr = rb + r;
        sX[r][c] = (gr < N_NODES) ? X[(size_t)gr * 64 + c] : 0.0f;
    }
    __syncthreads();
    int tr = (t >> 4) * 4;
    int tc = (t & 15) * 4;
    float acc[4][4] = {{0.f}};
#pragma unroll 8
    for (int k = 0; k < 64; ++k) {
        float xv[4], wv[4];
#pragma unroll
        for (int i = 0; i < 4; ++i) xv[i] = sX[tr + i][k];
#pragma unroll
        for (int j = 0; j < 4; ++j) wv[j] = sW[k][tc + j];
#pragma unroll
        for (int i = 0; i < 4; ++i)
#pragma unroll
            for (int j = 0; j < 4; ++j) acc[i][j] = fmaf(xv[i], wv[j], acc[i][j]);
    }
#pragma unroll
    for (int i = 0; i < 4; ++i) {
        int gr = rb + tr + i;
        if (gr < N_NODES) {
            float4 v = make_float4(acc[i][0], acc[i][1], acc[i][2], acc[i][3]);
            *reinterpret_cast<float4*>(&Y[(size_t)gr * 64 + tc]) = v;
        }
    }
}

// one wave per node, lane = feature. 8-wide MLP unroll on the edge gather.
// csr.y already holds w*dinv[src]; dinv[dst] applied at the end.
// MODE 0: OUT[i,f] = relu(agg + bias)       (full row, [N,64])
// MODE 1: h = relu(agg + bias); OUT[i] = dot(h, W3)  (scalar, [N])
template <int MODE>
__global__ __launch_bounds__(256) void k_agg64(const float* __restrict__ XW,
                                               const int2* __restrict__ csr,
                                               const int* __restrict__ rowptr,
                                               const float* __restrict__ dinv,
                                               const float* __restrict__ bias,
                                               float* __restrict__ OUT,
                                               const float* __restrict__ W3) {
    int wid = (blockIdx.x * 256 + threadIdx.x) >> 6;
    int f = threadIdx.x & 63;
    if (wid >= N_NODES) return;
    float di = dinv[wid];
    float self = XW[(size_t)wid * 64 + f];
    int beg = rowptr[wid], end = rowptr[wid + 1];
    float a[8] = {0.f, 0.f, 0.f, 0.f, 0.f, 0.f, 0.f, 0.f};
    for (int e = beg; e < end; e += 8) {
        int   idx[8];
        float w[8];
#pragma unroll
        for (int j = 0; j < 8; ++j) {
            int ee = e + j;
            int2 c = csr[ee < end ? ee : beg];          // always in-bounds
            idx[j] = c.x;
            w[j] = (ee < end) ? __int_as_float(c.y) : 0.0f;
        }
        float r[8];
#pragma unroll
        for (int j = 0; j < 8; ++j) r[j] = XW[(size_t)idx[j] * 64 + f];
#pragma unroll
        for (int j = 0; j < 8; ++j) a[j] = fmaf(w[j], r[j], a[j]);
    }
    float esum = ((a[0] + a[1]) + (a[2] + a[3])) + ((a[4] + a[5]) + (a[6] + a[7]));
    float acc = di * (di * self + esum) + bias[f];
    acc = fmaxf(acc, 0.0f);
    if (MODE == 0) {
        OUT[(size_t)wid * 64 + f] = acc;
    } else {
        float v = acc * W3[f];
#pragma unroll
        for (int off = 32; off > 0; off >>= 1) v += __shfl_down(v, off, 64);
        if (f == 0) OUT[wid] = v;
    }
}

// out[i] = b3 + di*(di*xw3[i] + sum_e v_e*xw3[src_e])   (4-wide MLP unroll)
__global__ __launch_bounds__(256) void k_agg_scalar(const float* __restrict__ xw3,
                                                    const int2* __restrict__ csr,
                                                    const int* __restrict__ rowptr,
                                                    const float* __restrict__ dinv,
                                                    const float* __restrict__ b3,
                                                    float* __restrict__ out) {
    int i = blockIdx.x * 256 + threadIdx.x;
    if (i >= N_NODES) return;
    float di = dinv[i];
    int beg = rowptr[i], end = rowptr[i + 1];
    float a0 = 0.f, a1 = 0.f, a2 = 0.f, a3 = 0.f;
    for (int e = beg; e < end; e += 4) {
        int2 c0 = csr[e];
        int2 c1 = csr[e + 1 < end ? e + 1 : beg];
        int2 c2 = csr[e + 2 < end ? e + 2 : beg];
        int2 c3 = csr[e + 3 < end ? e + 3 : beg];
        float w1 = (e + 1 < end) ? __int_as_float(c1.y) : 0.0f;
        float w2 = (e + 2 < end) ? __int_as_float(c2.y) : 0.0f;
        float w3 = (e + 3 < end) ? __int_as_float(c3.y) : 0.0f;
        a0 = fmaf(__int_as_float(c0.y), xw3[c0.x], a0);
        a1 = fmaf(w1, xw3[c1.x], a1);
        a2 = fmaf(w2, xw3[c2.x], a2);
        a3 = fmaf(w3, xw3[c3.x], a3);
    }
    out[i] = di * (di * xw3[i] + (a0 + a1) + (a2 + a3)) + b3[0];
}

// ---------------- launch ----------------

extern "C" void kernel_launch(void* const* d_in, const int* in_sizes, int n_in,
                              void* d_out, int out_size, void* d_ws, size_t ws_size,
                              hipStream_t stream) {
    const float* x  = (const float*)d_in[0];
    const int*   ei = (const int*)d_in[1];     // harness delivers integer inputs as int32
    const float* ea = (const float*)d_in[2];
    const float* W1 = (const float*)d_in[3];
    const float* b1 = (const float*)d_in[4];
    const float* W2 = (const float*)d_in[5];
    const float* b2 = (const float*)d_in[6];
    const float* W3 = (const float*)d_in[7];
    const float* b3 = (const float*)d_in[8];
    float* out = (float*)d_out;

    char* ws = (char*)d_ws;
    size_t off = 0;
    auto alloc = [&](size_t bytes) -> void* {
        void* p = ws + off;
        off = (off + bytes + 255) & ~(size_t)255;
        return p;
    };
    float* dinv   = (float*)alloc((size_t)N_NODES * 4);
    int*   cnt    = (int*)  alloc((size_t)N_NODES * 4);
    int*   rowptr = (int*)  alloc((size_t)(N_NODES + 1) * 4);
    int*   bsums  = (int*)  alloc(512 * 4);
    float* xw3    = (float*)alloc((size_t)N_NODES * 4);        // compact, L2-resident
    int2*  csr    = (int2*) alloc((size_t)N_EDGES * 8);
    float* bufA   = (float*)alloc((size_t)N_NODES * 64 * 4);
    float* bufB   = (float*)alloc((size_t)N_NODES * 64 * 4);
    int*   rank   = (int*)bufB;   // bufB first written by agg1, long after k_fill

    const int nbN = (N_NODES + 255) / 256;   // 391
    const int nbE = (N_EDGES + 255) / 256;   // 6250
    const int nbG = (N_NODES + 63) / 64;     // 1563 gemm blocks
    const int nbW = N_NODES / 4;             // 25000 (4 waves/block, 1 wave/node)

    k_init<<<nbN, 256, 0, stream>>>(cnt);
    k_histrank_gemm<<<NBH + NBG, 256, 0, stream>>>(ei + N_EDGES, cnt, rank, x, W1, bufA);
    k_scanA<<<nbN, 256, 0, stream>>>(cnt, rowptr, bsums);
    k_scanB<<<1, 512, 0, stream>>>(bsums, nbN);
    k_scanC<<<nbN, 256, 0, stream>>>(rowptr, bsums);
    k_fill<<<nbE, 256, 0, stream>>>(ei, ea, rank, rowptr, csr);
    k_deg<<<nbN, 256, 0, stream>>>(csr, rowptr, dinv);
    k_fold<<<nbE, 256, 0, stream>>>(csr, dinv);

    // layer 1 aggregation (gemm1 already done inside the hist dispatch)
    k_agg64<0><<<nbW, 256, 0, stream>>>(bufA, csr, rowptr, dinv, b1, bufB, nullptr);
    // layer 2 (+ fused layer-3 GEMV: h2 row stays in registers)
    k_gemm64<<<nbG, 256, 0, stream>>>(bufB, W2, bufA);
    k_agg64<1><<<nbW, 256, 0, stream>>>(bufA, csr, rowptr, dinv, b2, xw3, W3);
    // layer 3
    k_agg_scalar<<<nbN, 256, 0, stream>>>(xw3, csr, rowptr, dinv, b3, out);
}

// Round 6
// 316.960 us; speedup vs baseline: 1.9488x; 1.0957x over previous
//
#include <hip/hip_runtime.h>
#include <cstdint>

#define N_NODES 100000
#define N_EDGES 1600000
#define NBUCKET 196          // ceil(N_NODES / 512)
#define NPB_SHIFT 9
#define NPB 512              // nodes per bucket
#define P1_CHUNK 4096        // edges per partition block
#define NB_P1 391            // ceil(N_EDGES / P1_CHUNK)
#define NBG 1563             // gemm blocks (64 rows each)

// ---------------- bucketed CSR build (no global data atomics) ----------------

// P0: bucket totals via LDS histogram (only 196 global adds per block)
__global__ __launch_bounds__(256) void k_p0(const int* __restrict__ dst,
                                            int* __restrict__ btot) {
    __shared__ int bcnt[NBUCKET];
    int t = threadIdx.x;
    for (int i = t; i < NBUCKET; i += 256) bcnt[i] = 0;
    __syncthreads();
    int e0 = blockIdx.x * P1_CHUNK;
#pragma unroll
    for (int i = 0; i < 4; ++i) {
        int idx = e0 + (t + i * 256) * 4;
        if (idx + 3 < N_EDGES) {
            int4 d = *reinterpret_cast<const int4*>(&dst[idx]);
            atomicAdd(&bcnt[d.x >> NPB_SHIFT], 1);
            atomicAdd(&bcnt[d.y >> NPB_SHIFT], 1);
            atomicAdd(&bcnt[d.z >> NPB_SHIFT], 1);
            atomicAdd(&bcnt[d.w >> NPB_SHIFT], 1);
        }
    }
    __syncthreads();
    for (int i = t; i < NBUCKET; i += 256)
        if (bcnt[i]) atomicAdd(&btot[i], bcnt[i]);
}

// scan bucket totals -> segment bases; init global cursors
__global__ __launch_bounds__(256) void k_bscan(const int* __restrict__ btot,
                                               int* __restrict__ seg_base,
                                               int* __restrict__ gcursor) {
    __shared__ int tmp[256];
    int t = threadIdx.x;
    int v = (t < NBUCKET) ? btot[t] : 0;
    tmp[t] = v;
    __syncthreads();
    for (int off = 1; off < 256; off <<= 1) {
        int u = (t >= off) ? tmp[t - off] : 0;
        __syncthreads();
        tmp[t] += u;
        __syncthreads();
    }
    if (t < NBUCKET) { int ex = tmp[t] - v; seg_base[t] = ex; gcursor[t] = ex; }
    if (t == 0) seg_base[NBUCKET] = N_EDGES;
}

struct P1Shared {
    uint2 stage[P1_CHUNK];   // (d, eid) sorted by bucket      32768 B
    int cnt[256];
    int lbase[256];
    int gbase[256];
};
struct GemmShared { float sX[64][65]; float sW[64][65]; };

// P1: partition edges into bucket-ordered beidx (coalesced), fused with gemm1
__global__ __launch_bounds__(256) void k_p1gemm(const int* __restrict__ dst,
                                                int* gcursor,
                                                unsigned int* __restrict__ beidx,
                                                const float* __restrict__ X,
                                                const float* __restrict__ W,
                                                float* __restrict__ Y) {
    __shared__ union { P1Shared p; GemmShared g; } sm;
    int t = threadIdx.x;
    if (blockIdx.x < NB_P1) {
        for (int i = t; i < 256; i += 256) sm.p.cnt[i] = 0;
        __syncthreads();
        int e0 = blockIdx.x * P1_CHUNK;
        unsigned int dr[16];                       // (d<<12)|rank  (d<2^17, rank<4096)
#pragma unroll
        for (int i = 0; i < 4; ++i) {
            int idx = e0 + (t + i * 256) * 4;
            if (idx + 3 < N_EDGES) {
                int4 d4 = *reinterpret_cast<const int4*>(&dst[idx]);
                int r0 = atomicAdd(&sm.p.cnt[d4.x >> NPB_SHIFT], 1);
                int r1 = atomicAdd(&sm.p.cnt[d4.y >> NPB_SHIFT], 1);
                int r2 = atomicAdd(&sm.p.cnt[d4.z >> NPB_SHIFT], 1);
                int r3 = atomicAdd(&sm.p.cnt[d4.w >> NPB_SHIFT], 1);
                dr[i * 4 + 0] = ((unsigned)d4.x << 12) | (unsigned)r0;
                dr[i * 4 + 1] = ((unsigned)d4.y << 12) | (unsigned)r1;
                dr[i * 4 + 2] = ((unsigned)d4.z << 12) | (unsigned)r2;
                dr[i * 4 + 3] = ((unsigned)d4.w << 12) | (unsigned)r3;
            } else {
#pragma unroll
                for (int k = 0; k < 4; ++k) dr[i * 4 + k] = 0xFFFFFFFFu;
            }
        }
        __syncthreads();
        // scan cnt (padded 256) -> exclusive lbase; reserve global space
        int v = sm.p.cnt[t];
        sm.p.lbase[t] = v;
        __syncthreads();
        for (int off = 1; off < 256; off <<= 1) {
            int u = (t >= off) ? sm.p.lbase[t - off] : 0;
            __syncthreads();
            sm.p.lbase[t] += u;
            __syncthreads();
        }
        int ex = sm.p.lbase[t] - v;
        if (t < NBUCKET) sm.p.gbase[t] = atomicAdd(&gcursor[t], v);
        __syncthreads();
        sm.p.lbase[t] = ex;
        __syncthreads();
        // stage bucket-sorted
#pragma unroll
        for (int j = 0; j < 16; ++j) {
            if (dr[j] != 0xFFFFFFFFu) {
                int d = dr[j] >> 12, r = dr[j] & 0xFFF, b = d >> NPB_SHIFT;
                int eid = e0 + ((t + (j >> 2) * 256) << 2) + (j & 3);
                sm.p.stage[sm.p.lbase[b] + r] = make_uint2((unsigned)d, (unsigned)eid);
            }
        }
        __syncthreads();
        // stream out coalesced runs: beidx = (dloc<<21) | eid
        int n_valid = min(P1_CHUNK, N_EDGES - e0);
        for (int j = t; j < n_valid; j += 256) {
            uint2 de = sm.p.stage[j];
            int b = (int)(de.x >> NPB_SHIFT);
            int pos = sm.p.gbase[b] + (j - sm.p.lbase[b]);
            beidx[pos] = ((de.x & (NPB - 1u)) << 21) | de.y;
        }
        return;
    }
    // ---- gemm1: Y = X @ W ----
    int rb = (blockIdx.x - NB_P1) * 64;
#pragma unroll
    for (int i = 0; i < 16; ++i) {
        int idx = t + i * 256;
        int r = idx >> 6, c = idx & 63;
        sm.g.sW[r][c] = W[idx];
        int gr = rb + r;
        sm.g.sX[r][c] = (gr < N_NODES) ? X[(size_t)gr * 64 + c] : 0.0f;
    }
    __syncthreads();
    int tr = (t >> 4) * 4;
    int tc = (t & 15) * 4;
    float acc[4][4] = {{0.f}};
#pragma unroll 8
    for (int k = 0; k < 64; ++k) {
        float xv[4], wv[4];
#pragma unroll
        for (int i = 0; i < 4; ++i) xv[i] = sm.g.sX[tr + i][k];
#pragma unroll
        for (int j = 0; j < 4; ++j) wv[j] = sm.g.sW[k][tc + j];
#pragma unroll
        for (int i = 0; i < 4; ++i)
#pragma unroll
            for (int j = 0; j < 4; ++j) acc[i][j] = fmaf(xv[i], wv[j], acc[i][j]);
    }
#pragma unroll
    for (int i = 0; i < 4; ++i) {
        int gr = rb + tr + i;
        if (gr < N_NODES) {
            float4 v = make_float4(acc[i][0], acc[i][1], acc[i][2], acc[i][3]);
            *reinterpret_cast<float4*>(&Y[(size_t)gr * 64 + tc]) = v;
        }
    }
}

// P2: per-bucket LDS hist + scan -> rowptr, csr=(src,w), dinv (deg via LDS f32 atomics)
__global__ __launch_bounds__(1024) void k_p2(const unsigned int* __restrict__ beidx,
                                             const int* __restrict__ seg_base,
                                             const int* __restrict__ srcarr,
                                             const float* __restrict__ ea,
                                             int* __restrict__ rank_g,
                                             int* __restrict__ rowptr,
                                             int2* __restrict__ csr,
                                             float* __restrict__ dinv) {
    __shared__ int cnt[NPB];
    __shared__ int lrp[NPB];
    __shared__ float degw[NPB];
    int t = threadIdx.x;
    int b = blockIdx.x;
    if (t < NPB) { cnt[t] = 0; degw[t] = 0.0f; }
    __syncthreads();
    int segb = seg_base[b], sege = seg_base[b + 1];
    for (int j = segb + t; j < sege; j += 1024) {
        unsigned int v = beidx[j];
        rank_g[j] = atomicAdd(&cnt[v >> 21], 1);
    }
    __syncthreads();
    int own = (t < NPB) ? cnt[t] : 0;
    if (t < NPB) lrp[t] = own;
    __syncthreads();
    for (int off = 1; off < NPB; off <<= 1) {
        int u = (t >= off && t < NPB) ? lrp[t - off] : 0;
        __syncthreads();
        if (t < NPB) lrp[t] += u;
        __syncthreads();
    }
    if (t < NPB) lrp[t] -= own;          // exclusive
    __syncthreads();
    int node = (b << NPB_SHIFT) + t;
    if (t < NPB && node <= N_NODES) rowptr[node] = segb + lrp[t];
    for (int j = segb + t; j < sege; j += 1024) {
        unsigned int v = beidx[j];
        int dloc = (int)(v >> 21);
        int eid = (int)(v & 0x1FFFFFu);
        int r = rank_g[j];
        float tt = ea[eid] * (1.0f / 200.0f);
        float w = __expf(-tt * tt);
        int s = srcarr[eid];
        csr[segb + lrp[dloc] + r] = make_int2(s, __float_as_int(w));
        atomicAdd(&degw[dloc], w);
    }
    __syncthreads();
    if (t < NPB && node < N_NODES) dinv[node] = rsqrtf(1.0f + degw[t]);
}

// csr[e].w *= dinv[src]  (dinv[dst] factored out algebraically in agg)
__global__ __launch_bounds__(256) void k_fold(int2* csr, const float* __restrict__ dinv) {
    int e = blockIdx.x * 256 + threadIdx.x;
    if (e >= N_EDGES) return;
    int2 c = csr[e];
    c.y = __float_as_int(__int_as_float(c.y) * dinv[c.x]);
    csr[e] = c;
}

// ---------------- dense compute ----------------

__global__ __launch_bounds__(256) void k_gemm64(const float* __restrict__ X,
                                                const float* __restrict__ W,
                                                float* __restrict__ Y) {
    __shared__ float sX[64][65];
    __shared__ float sW[64][65];
    int t = threadIdx.x;
    int rb = blockIdx.x * 64;
#pragma unroll
    for (int i = 0; i < 16; ++i) {
        int idx = t + i * 256;
        int r = idx >> 6, c = idx & 63;
        sW[r][c] = W[idx];
        int gr = rb + r;
        sX[r][c] = (gr < N_NODES) ? X[(size_t)gr * 64 + c] : 0.0f;
    }
    __syncthreads();
    int tr = (t >> 4) * 4;
    int tc = (t & 15) * 4;
    float acc[4][4] = {{0.f}};
#pragma unroll 8
    for (int k = 0; k < 64; ++k) {
        float xv[4], wv[4];
#pragma unroll
        for (int i = 0; i < 4; ++i) xv[i] = sX[tr + i][k];
#pragma unroll
        for (int j = 0; j < 4; ++j) wv[j] = sW[k][tc + j];
#pragma unroll
        for (int i = 0; i < 4; ++i)
#pragma unroll
            for (int j = 0; j < 4; ++j) acc[i][j] = fmaf(xv[i], wv[j], acc[i][j]);
    }
#pragma unroll
    for (int i = 0; i < 4; ++i) {
        int gr = rb + tr + i;
        if (gr < N_NODES) {
            float4 v = make_float4(acc[i][0], acc[i][1], acc[i][2], acc[i][3]);
            *reinterpret_cast<float4*>(&Y[(size_t)gr * 64 + tc]) = v;
        }
    }
}

// one wave per node, lane = feature; 8-wide MLP unroll on the edge gather.
// MODE 0: OUT[i,f] = relu(agg + bias);  MODE 1: fused W3 dot -> OUT[i]
template <int MODE>
__global__ __launch_bounds__(256) void k_agg64(const float* __restrict__ XW,
                                               const int2* __restrict__ csr,
                                               const int* __restrict__ rowptr,
                                               const float* __restrict__ dinv,
                                               const float* __restrict__ bias,
                                               float* __restrict__ OUT,
                                               const float* __restrict__ W3) {
    int wid = (blockIdx.x * 256 + threadIdx.x) >> 6;
    int f = threadIdx.x & 63;
    if (wid >= N_NODES) return;
    float di = dinv[wid];
    float self = XW[(size_t)wid * 64 + f];
    int beg = rowptr[wid], end = rowptr[wid + 1];
    float a[8] = {0.f, 0.f, 0.f, 0.f, 0.f, 0.f, 0.f, 0.f};
    for (int e = beg; e < end; e += 8) {
        int   idx[8];
        float w[8];
#pragma unroll
        for (int j = 0; j < 8; ++j) {
            int ee = e + j;
            int2 c = csr[ee < end ? ee : beg];
            idx[j] = c.x;
            w[j] = (ee < end) ? __int_as_float(c.y) : 0.0f;
        }
        float r[8];
#pragma unroll
        for (int j = 0; j < 8; ++j) r[j] = XW[(size_t)idx[j] * 64 + f];
#pragma unroll
        for (int j = 0; j < 8; ++j) a[j] = fmaf(w[j], r[j], a[j]);
    }
    float esum = ((a[0] + a[1]) + (a[2] + a[3])) + ((a[4] + a[5]) + (a[6] + a[7]));
    float acc = di * (di * self + esum) + bias[f];
    acc = fmaxf(acc, 0.0f);
    if (MODE == 0) {
        OUT[(size_t)wid * 64 + f] = acc;
    } else {
        float v = acc * W3[f];
#pragma unroll
        for (int off = 32; off > 0; off >>= 1) v += __shfl_down(v, off, 64);
        if (f == 0) OUT[wid] = v;
    }
}

__global__ __launch_bounds__(256) void k_agg_scalar(const float* __restrict__ xw3,
                                                    const int2* __restrict__ csr,
                                                    const int* __restrict__ rowptr,
                                                    const float* __restrict__ dinv,
                                                    const float* __restrict__ b3,
                                                    float* __restrict__ out) {
    int i = blockIdx.x * 256 + threadIdx.x;
    if (i >= N_NODES) return;
    float di = dinv[i];
    int beg = rowptr[i], end = rowptr[i + 1];
    float a0 = 0.f, a1 = 0.f, a2 = 0.f, a3 = 0.f;
    for (int e = beg; e < end; e += 4) {
        int2 c0 = csr[e];
        int2 c1 = csr[e + 1 < end ? e + 1 : beg];
        int2 c2 = csr[e + 2 < end ? e + 2 : beg];
        int2 c3 = csr[e + 3 < end ? e + 3 : beg];
        float w1 = (e + 1 < end) ? __int_as_float(c1.y) : 0.0f;
        float w2 = (e + 2 < end) ? __int_as_float(c2.y) : 0.0f;
        float w3 = (e + 3 < end) ? __int_as_float(c3.y) : 0.0f;
        a0 = fmaf(__int_as_float(c0.y), xw3[c0.x], a0);
        a1 = fmaf(w1, xw3[c1.x], a1);
        a2 = fmaf(w2, xw3[c2.x], a2);
        a3 = fmaf(w3, xw3[c3.x], a3);
    }
    out[i] = di * (di * xw3[i] + (a0 + a1) + (a2 + a3)) + b3[0];
}

// ---------------- launch ----------------

extern "C" void kernel_launch(void* const* d_in, const int* in_sizes, int n_in,
                              void* d_out, int out_size, void* d_ws, size_t ws_size,
                              hipStream_t stream) {
    const float* x  = (const float*)d_in[0];
    const int*   ei = (const int*)d_in[1];     // int32 per harness contract
    const float* ea = (const float*)d_in[2];
    const float* W1 = (const float*)d_in[3];
    const float* b1 = (const float*)d_in[4];
    const float* W2 = (const float*)d_in[5];
    const float* b2 = (const float*)d_in[6];
    const float* W3 = (const float*)d_in[7];
    const float* b3 = (const float*)d_in[8];
    float* out = (float*)d_out;
    const int* srcarr = ei;
    const int* dstarr = ei + N_EDGES;

    char* ws = (char*)d_ws;
    size_t off = 0;
    auto alloc = [&](size_t bytes) -> void* {
        void* p = ws + off;
        off = (off + bytes + 255) & ~(size_t)255;
        return p;
    };
    float* dinv     = (float*)alloc((size_t)N_NODES * 4);
    int*   rowptr   = (int*)  alloc((size_t)(N_NODES + 1) * 4);
    int*   btot     = (int*)  alloc(NBUCKET * 4);
    int*   seg_base = (int*)  alloc((NBUCKET + 1) * 4);
    int*   gcursor  = (int*)  alloc(NBUCKET * 4);
    float* xw3      = (float*)alloc((size_t)N_NODES * 4);
    unsigned int* beidx = (unsigned int*)alloc((size_t)N_EDGES * 4);
    int2*  csr      = (int2*) alloc((size_t)N_EDGES * 8);
    float* bufA     = (float*)alloc((size_t)N_NODES * 64 * 4);
    float* bufB     = (float*)alloc((size_t)N_NODES * 64 * 4);
    int*   rank_g   = (int*)bufB;   // bufB first real write is agg1 output (after P2)

    const int nbE = (N_EDGES + 255) / 256;   // 6250
    const int nbW = N_NODES / 4;             // 25000
    const int nbN = (N_NODES + 255) / 256;   // 391

    hipMemsetAsync(btot, 0, NBUCKET * 4, stream);
    k_p0<<<NB_P1, 256, 0, stream>>>(dstarr, btot);
    k_bscan<<<1, 256, 0, stream>>>(btot, seg_base, gcursor);
    k_p1gemm<<<NB_P1 + NBG, 256, 0, stream>>>(dstarr, gcursor, beidx, x, W1, bufA);
    k_p2<<<NBUCKET, 1024, 0, stream>>>(beidx, seg_base, srcarr, ea,
                                       rank_g, rowptr, csr, dinv);
    k_fold<<<nbE, 256, 0, stream>>>(csr, dinv);

    k_agg64<0><<<nbW, 256, 0, stream>>>(bufA, csr, rowptr, dinv, b1, bufB, nullptr);
    k_gemm64<<<NBG, 256, 0, stream>>>(bufB, W2, bufA);
    k_agg64<1><<<nbW, 256, 0, stream>>>(bufA, csr, rowptr, dinv, b2, xw3, W3);
    k_agg_scalar<<<nbN, 256, 0, stream>>>(xw3, csr, rowptr, dinv, b3, out);
}

// Round 8
// 312.319 us; speedup vs baseline: 1.9778x; 1.0149x over previous
//
#include <hip/hip_runtime.h>
#include <cstdint>

#define N_NODES 100000
#define N_EDGES 1600000
#define NBUCKET 196          // ceil(N_NODES / 512)
#define NPB_SHIFT 9
#define NPB 512              // nodes per bucket
#define P1_CHUNK 4096        // edges per partition block
#define NB_P1 391            // ceil(N_EDGES / P1_CHUNK)
#define NBG 1563             // gemm blocks (64 rows each)
#define PAD_RESERVE (NPB * 8)                 // worst-case per-bucket padding
#define NSLOT (N_EDGES + NBUCKET * PAD_RESERVE)   // 2,402,816 padded csr slots

typedef int iv4 __attribute__((ext_vector_type(4)));   // nontemporal-load-compatible

// ---------------- bucketed CSR build (no global data atomics) ----------------

__global__ __launch_bounds__(256) void k_p0(const int* __restrict__ dst,
                                            int* __restrict__ btot) {
    __shared__ int bcnt[NBUCKET];
    int t = threadIdx.x;
    for (int i = t; i < NBUCKET; i += 256) bcnt[i] = 0;
    __syncthreads();
    int e0 = blockIdx.x * P1_CHUNK;
#pragma unroll
    for (int i = 0; i < 4; ++i) {
        int idx = e0 + (t + i * 256) * 4;
        if (idx + 3 < N_EDGES) {
            int4 d = *reinterpret_cast<const int4*>(&dst[idx]);
            atomicAdd(&bcnt[d.x >> NPB_SHIFT], 1);
            atomicAdd(&bcnt[d.y >> NPB_SHIFT], 1);
            atomicAdd(&bcnt[d.z >> NPB_SHIFT], 1);
            atomicAdd(&bcnt[d.w >> NPB_SHIFT], 1);
        }
    }
    __syncthreads();
    for (int i = t; i < NBUCKET; i += 256)
        if (bcnt[i]) atomicAdd(&btot[i], bcnt[i]);
}

__global__ __launch_bounds__(256) void k_bscan(const int* __restrict__ btot,
                                               int* __restrict__ seg_base,
                                               int* __restrict__ gcursor) {
    __shared__ int tmp[256];
    int t = threadIdx.x;
    int v = (t < NBUCKET) ? btot[t] : 0;
    tmp[t] = v;
    __syncthreads();
    for (int off = 1; off < 256; off <<= 1) {
        int u = (t >= off) ? tmp[t - off] : 0;
        __syncthreads();
        tmp[t] += u;
        __syncthreads();
    }
    if (t < NBUCKET) { int ex = tmp[t] - v; seg_base[t] = ex; gcursor[t] = ex; }
    if (t == 0) seg_base[NBUCKET] = N_EDGES;
}

struct P1Shared {
    uint2 stage[P1_CHUNK];
    int cnt[256];
    int lbase[256];
    int gbase[256];
};
struct GemmShared { float sX[64][65]; float sW[64][65]; };

// P1: partition edges into bucket-ordered beidx (coalesced), fused with gemm1
__global__ __launch_bounds__(256) void k_p1gemm(const int* __restrict__ dst,
                                                int* gcursor,
                                                unsigned int* __restrict__ beidx,
                                                const float* __restrict__ X,
                                                const float* __restrict__ W,
                                                float* __restrict__ Y) {
    __shared__ union { P1Shared p; GemmShared g; } sm;
    int t = threadIdx.x;
    if (blockIdx.x < NB_P1) {
        for (int i = t; i < 256; i += 256) sm.p.cnt[i] = 0;
        __syncthreads();
        int e0 = blockIdx.x * P1_CHUNK;
        unsigned int dr[16];                       // (d<<12)|rank
#pragma unroll
        for (int i = 0; i < 4; ++i) {
            int idx = e0 + (t + i * 256) * 4;
            if (idx + 3 < N_EDGES) {
                int4 d4 = *reinterpret_cast<const int4*>(&dst[idx]);
                int r0 = atomicAdd(&sm.p.cnt[d4.x >> NPB_SHIFT], 1);
                int r1 = atomicAdd(&sm.p.cnt[d4.y >> NPB_SHIFT], 1);
                int r2 = atomicAdd(&sm.p.cnt[d4.z >> NPB_SHIFT], 1);
                int r3 = atomicAdd(&sm.p.cnt[d4.w >> NPB_SHIFT], 1);
                dr[i * 4 + 0] = ((unsigned)d4.x << 12) | (unsigned)r0;
                dr[i * 4 + 1] = ((unsigned)d4.y << 12) | (unsigned)r1;
                dr[i * 4 + 2] = ((unsigned)d4.z << 12) | (unsigned)r2;
                dr[i * 4 + 3] = ((unsigned)d4.w << 12) | (unsigned)r3;
            } else {
#pragma unroll
                for (int k = 0; k < 4; ++k) dr[i * 4 + k] = 0xFFFFFFFFu;
            }
        }
        __syncthreads();
        int v = sm.p.cnt[t];
        sm.p.lbase[t] = v;
        __syncthreads();
        for (int off = 1; off < 256; off <<= 1) {
            int u = (t >= off) ? sm.p.lbase[t - off] : 0;
            __syncthreads();
            sm.p.lbase[t] += u;
            __syncthreads();
        }
        int ex = sm.p.lbase[t] - v;
        if (t < NBUCKET) sm.p.gbase[t] = atomicAdd(&gcursor[t], v);
        __syncthreads();
        sm.p.lbase[t] = ex;
        __syncthreads();
#pragma unroll
        for (int j = 0; j < 16; ++j) {
            if (dr[j] != 0xFFFFFFFFu) {
                int d = dr[j] >> 12, r = dr[j] & 0xFFF, b = d >> NPB_SHIFT;
                int eid = e0 + ((t + (j >> 2) * 256) << 2) + (j & 3);
                sm.p.stage[sm.p.lbase[b] + r] = make_uint2((unsigned)d, (unsigned)eid);
            }
        }
        __syncthreads();
        int n_valid = min(P1_CHUNK, N_EDGES - e0);
        for (int j = t; j < n_valid; j += 256) {
            uint2 de = sm.p.stage[j];
            int b = (int)(de.x >> NPB_SHIFT);
            int pos = sm.p.gbase[b] + (j - sm.p.lbase[b]);
            beidx[pos] = ((de.x & (NPB - 1u)) << 21) | de.y;
        }
        return;
    }
    // ---- gemm1: Y = X @ W ----
    int rb = (blockIdx.x - NB_P1) * 64;
#pragma unroll
    for (int i = 0; i < 16; ++i) {
        int idx = t + i * 256;
        int r = idx >> 6, c = idx & 63;
        sm.g.sW[r][c] = W[idx];
        int gr = rb + r;
        sm.g.sX[r][c] = (gr < N_NODES) ? X[(size_t)gr * 64 + c] : 0.0f;
    }
    __syncthreads();
    int tr = (t >> 4) * 4;
    int tc = (t & 15) * 4;
    float acc[4][4] = {{0.f}};
#pragma unroll 8
    for (int k = 0; k < 64; ++k) {
        float xv[4], wv[4];
#pragma unroll
        for (int i = 0; i < 4; ++i) xv[i] = sm.g.sX[tr + i][k];
#pragma unroll
        for (int j = 0; j < 4; ++j) wv[j] = sm.g.sW[k][tc + j];
#pragma unroll
        for (int i = 0; i < 4; ++i)
#pragma unroll
            for (int j = 0; j < 4; ++j) acc[i][j] = fmaf(xv[i], wv[j], acc[i][j]);
    }
#pragma unroll
    for (int i = 0; i < 4; ++i) {
        int gr = rb + tr + i;
        if (gr < N_NODES) {
            float4 v = make_float4(acc[i][0], acc[i][1], acc[i][2], acc[i][3]);
            *reinterpret_cast<float4*>(&Y[(size_t)gr * 64 + tc]) = v;
        }
    }
}

// P2: per-bucket LDS hist+scan -> PADDED csr rows (mult of 8), rowinfo, dinv
__global__ __launch_bounds__(1024) void k_p2(const unsigned int* __restrict__ beidx,
                                             const int* __restrict__ seg_base,
                                             const int* __restrict__ srcarr,
                                             const float* __restrict__ ea,
                                             int* __restrict__ rank_g,
                                             int2* __restrict__ rowinfo,
                                             int2* __restrict__ csr,
                                             float* __restrict__ dinv) {
    __shared__ int cnt[NPB];
    __shared__ int prp[NPB];
    __shared__ float degw[NPB];
    __shared__ int stot;
    int t = threadIdx.x;
    int b = blockIdx.x;
    if (t < NPB) { cnt[t] = 0; degw[t] = 0.0f; }
    __syncthreads();
    int segb = seg_base[b], sege = seg_base[b + 1];
    int pbase = segb + b * PAD_RESERVE;
    for (int j = segb + t; j < sege; j += 1024) {
        rank_g[j] = atomicAdd(&cnt[beidx[j] >> 21], 1);
    }
    __syncthreads();
    int raw = (t < NPB) ? cnt[t] : 0;
    int pad = (raw + 7) & ~7;
    if (t < NPB) prp[t] = pad;
    __syncthreads();
    for (int off = 1; off < NPB; off <<= 1) {
        int u = (t >= off && t < NPB) ? prp[t - off] : 0;
        __syncthreads();
        if (t < NPB) prp[t] += u;
        __syncthreads();
    }
    if (t == NPB - 1) stot = prp[t];          // total padded size
    if (t < NPB) prp[t] -= pad;               // exclusive
    __syncthreads();
    int node = (b << NPB_SHIFT) + t;
    if (t < NPB && node < N_NODES)
        rowinfo[node] = make_int2(pbase + prp[t], pad >> 3);
    // scatter edges
    for (int j = segb + t; j < sege; j += 1024) {
        unsigned int v = beidx[j];
        int dloc = (int)(v >> 21);
        int eid = (int)(v & 0x1FFFFFu);
        int r = rank_g[j];
        float tt = ea[eid] * (1.0f / 200.0f);
        float w = __expf(-tt * tt);
        csr[pbase + prp[dloc] + r] = make_int2(srcarr[eid], __float_as_int(w));
        atomicAdd(&degw[dloc], w);
    }
    __syncthreads();
    // per-node padding (src = self: L1-warm row, w = 0) + dinv
    if (t < NPB && node < N_NODES) {
        dinv[node] = rsqrtf(1.0f + degw[t]);
        int begin = pbase + prp[t];
        for (int j = raw; j < pad; ++j) csr[begin + j] = make_int2(node, 0);
    }
    // gap fill so k_fold can stream the whole padded array safely
    int rawsz = sege - segb;
    for (int j = stot + t; j < rawsz + PAD_RESERVE; j += 1024)
        csr[pbase + j] = make_int2(0, 0);
}

// csr[e].w *= dinv[src]  (dinv[dst] factored out algebraically in agg)
__global__ __launch_bounds__(256) void k_fold(int2* csr, const float* __restrict__ dinv) {
    int e = blockIdx.x * 256 + threadIdx.x;
    if (e >= NSLOT) return;
    int2 c = csr[e];
    c.y = __float_as_int(__int_as_float(c.y) * dinv[c.x]);
    csr[e] = c;
}

// ---------------- dense compute ----------------

__global__ __launch_bounds__(256) void k_gemm64(const float* __restrict__ X,
                                                const float* __restrict__ W,
                                                float* __restrict__ Y) {
    __shared__ float sX[64][65];
    __shared__ float sW[64][65];
    int t = threadIdx.x;
    int rb = blockIdx.x * 64;
#pragma unroll
    for (int i = 0; i < 16; ++i) {
        int idx = t + i * 256;
        int r = idx >> 6, c = idx & 63;
        sW[r][c] = W[idx];
        int gr = rb + r;
        sX[r][c] = (gr < N_NODES) ? X[(size_t)gr * 64 + c] : 0.0f;
    }
    __syncthreads();
    int tr = (t >> 4) * 4;
    int tc = (t & 15) * 4;
    float acc[4][4] = {{0.f}};
#pragma unroll 8
    for (int k = 0; k < 64; ++k) {
        float xv[4], wv[4];
#pragma unroll
        for (int i = 0; i < 4; ++i) xv[i] = sX[tr + i][k];
#pragma unroll
        for (int j = 0; j < 4; ++j) wv[j] = sW[k][tc + j];
#pragma unroll
        for (int i = 0; i < 4; ++i)
#pragma unroll
            for (int j = 0; j < 4; ++j) acc[i][j] = fmaf(xv[i], wv[j], acc[i][j]);
    }
#pragma unroll
    for (int i = 0; i < 4; ++i) {
        int gr = rb + tr + i;
        if (gr < N_NODES) {
            float4 v = make_float4(acc[i][0], acc[i][1], acc[i][2], acc[i][3]);
            *reinterpret_cast<float4*>(&Y[(size_t)gr * 64 + tc]) = v;
        }
    }
}

// one wave per node, lane = feature. Padded rows: NO bounds checks.
// csr.y holds w*dinv[src]; dinv[dst] applied at the end.
// MODE 0: OUT[i,f] = relu(agg + bias);  MODE 1: fused W3 dot -> OUT[i]
template <int MODE>
__global__ __launch_bounds__(256) void k_agg64(const float* __restrict__ XW,
                                               const int2* __restrict__ csr,
                                               const int2* __restrict__ rowinfo,
                                               const float* __restrict__ dinv,
                                               const float* __restrict__ bias,
                                               float* __restrict__ OUT,
                                               const float* __restrict__ W3) {
    int wid = (blockIdx.x * 256 + threadIdx.x) >> 6;
    unsigned f = threadIdx.x & 63;
    if (wid >= N_NODES) return;
    float di = dinv[wid];
    float self = XW[((unsigned)wid << 6) + f];
    int2 ri = rowinfo[wid];
    const iv4* p = reinterpret_cast<const iv4*>(csr + ri.x);
    int nb = ri.y;
    float a[8] = {0.f, 0.f, 0.f, 0.f, 0.f, 0.f, 0.f, 0.f};
    for (int it = 0; it < nb; ++it, p += 4) {
        iv4 q0 = __builtin_nontemporal_load(p);
        iv4 q1 = __builtin_nontemporal_load(p + 1);
        iv4 q2 = __builtin_nontemporal_load(p + 2);
        iv4 q3 = __builtin_nontemporal_load(p + 3);
        float r0 = XW[((unsigned)q0.x << 6) + f];
        float r1 = XW[((unsigned)q0.z << 6) + f];
        float r2 = XW[((unsigned)q1.x << 6) + f];
        float r3 = XW[((unsigned)q1.z << 6) + f];
        float r4 = XW[((unsigned)q2.x << 6) + f];
        float r5 = XW[((unsigned)q2.z << 6) + f];
        float r6 = XW[((unsigned)q3.x << 6) + f];
        float r7 = XW[((unsigned)q3.z << 6) + f];
        a[0] = fmaf(__int_as_float(q0.y), r0, a[0]);
        a[1] = fmaf(__int_as_float(q0.w), r1, a[1]);
        a[2] = fmaf(__int_as_float(q1.y), r2, a[2]);
        a[3] = fmaf(__int_as_float(q1.w), r3, a[3]);
        a[4] = fmaf(__int_as_float(q2.y), r4, a[4]);
        a[5] = fmaf(__int_as_float(q2.w), r5, a[5]);
        a[6] = fmaf(__int_as_float(q3.y), r6, a[6]);
        a[7] = fmaf(__int_as_float(q3.w), r7, a[7]);
    }
    float esum = ((a[0] + a[1]) + (a[2] + a[3])) + ((a[4] + a[5]) + (a[6] + a[7]));
    float acc = di * (di * self + esum) + bias[f];
    acc = fmaxf(acc, 0.0f);
    if (MODE == 0) {
        OUT[((unsigned)wid << 6) + f] = acc;
    } else {
        float v = acc * W3[f];
#pragma unroll
        for (int off = 32; off > 0; off >>= 1) v += __shfl_down(v, off, 64);
        if (f == 0) OUT[wid] = v;
    }
}

// out[i] = b3 + di*(di*xw3[i] + sum_e v_e*xw3[src_e])  (padded rows, no checks)
__global__ __launch_bounds__(256) void k_agg_scalar(const float* __restrict__ xw3,
                                                    const int2* __restrict__ csr,
                                                    const int2* __restrict__ rowinfo,
                                                    const float* __restrict__ dinv,
                                                    const float* __restrict__ b3,
                                                    float* __restrict__ out) {
    int i = blockIdx.x * 256 + threadIdx.x;
    if (i >= N_NODES) return;
    float di = dinv[i];
    int2 ri = rowinfo[i];
    const iv4* p = reinterpret_cast<const iv4*>(csr + ri.x);
    int nb = ri.y;
    float a0 = 0.f, a1 = 0.f, a2 = 0.f, a3 = 0.f;
    for (int it = 0; it < nb; ++it, p += 4) {
        iv4 q0 = __builtin_nontemporal_load(p);
        iv4 q1 = __builtin_nontemporal_load(p + 1);
        iv4 q2 = __builtin_nontemporal_load(p + 2);
        iv4 q3 = __builtin_nontemporal_load(p + 3);
        a0 = fmaf(__int_as_float(q0.y), xw3[q0.x], a0);
        a1 = fmaf(__int_as_float(q0.w), xw3[q0.z], a1);
        a2 = fmaf(__int_as_float(q1.y), xw3[q1.x], a2);
        a3 = fmaf(__int_as_float(q1.w), xw3[q1.z], a3);
        a0 = fmaf(__int_as_float(q2.y), xw3[q2.x], a0);
        a1 = fmaf(__int_as_float(q2.w), xw3[q2.z], a1);
        a2 = fmaf(__int_as_float(q3.y), xw3[q3.x], a2);
        a3 = fmaf(__int_as_float(q3.w), xw3[q3.z], a3);
    }
    out[i] = di * (di * xw3[i] + (a0 + a1) + (a2 + a3)) + b3[0];
}

// ---------------- launch ----------------

extern "C" void kernel_launch(void* const* d_in, const int* in_sizes, int n_in,
                              void* d_out, int out_size, void* d_ws, size_t ws_size,
                              hipStream_t stream) {
    const float* x  = (const float*)d_in[0];
    const int*   ei = (const int*)d_in[1];     // int32 per harness contract
    const float* ea = (const float*)d_in[2];
    const float* W1 = (const float*)d_in[3];
    const float* b1 = (const float*)d_in[4];
    const float* W2 = (const float*)d_in[5];
    const float* b2 = (const float*)d_in[6];
    const float* W3 = (const float*)d_in[7];
    const float* b3 = (const float*)d_in[8];
    float* out = (float*)d_out;
    const int* srcarr = ei;
    const int* dstarr = ei + N_EDGES;

    char* ws = (char*)d_ws;
    size_t off = 0;
    auto alloc = [&](size_t bytes) -> void* {
        void* p = ws + off;
        off = (off + bytes + 255) & ~(size_t)255;
        return p;
    };
    float* dinv     = (float*)alloc((size_t)N_NODES * 4);
    int2*  rowinfo  = (int2*) alloc((size_t)N_NODES * 8);
    int*   btot     = (int*)  alloc(NBUCKET * 4);
    int*   seg_base = (int*)  alloc((NBUCKET + 1) * 4);
    int*   gcursor  = (int*)  alloc(NBUCKET * 4);
    float* xw3      = (float*)alloc((size_t)N_NODES * 4);
    unsigned int* beidx = (unsigned int*)alloc((size_t)N_EDGES * 4);
    int2*  csr      = (int2*) alloc((size_t)NSLOT * 8);
    float* bufA     = (float*)alloc((size_t)N_NODES * 64 * 4);
    float* bufB     = (float*)alloc((size_t)N_NODES * 64 * 4);
    int*   rank_g   = (int*)bufB;   // bufB's first real write (agg1) is after P2

    const int nbW = N_NODES / 4;             // 25000
    const int nbN = (N_NODES + 255) / 256;   // 391
    const int nbF = (NSLOT + 255) / 256;     // 9387

    hipMemsetAsync(btot, 0, NBUCKET * 4, stream);
    k_p0<<<NB_P1, 256, 0, stream>>>(dstarr, btot);
    k_bscan<<<1, 256, 0, stream>>>(btot, seg_base, gcursor);
    k_p1gemm<<<NB_P1 + NBG, 256, 0, stream>>>(dstarr, gcursor, beidx, x, W1, bufA);
    k_p2<<<NBUCKET, 1024, 0, stream>>>(beidx, seg_base, srcarr, ea,
                                       rank_g, rowinfo, csr, dinv);
    k_fold<<<nbF, 256, 0, stream>>>(csr, dinv);

    k_agg64<0><<<nbW, 256, 0, stream>>>(bufA, csr, rowinfo, dinv, b1, bufB, nullptr);
    k_gemm64<<<NBG, 256, 0, stream>>>(bufB, W2, bufA);
    k_agg64<1><<<nbW, 256, 0, stream>>>(bufA, csr, rowinfo, dinv, b2, xw3, W3);
    k_agg_scalar<<<nbN, 256, 0, stream>>>(xw3, csr, rowinfo, dinv, b3, out);
}

// Round 9
// 296.315 us; speedup vs baseline: 2.0846x; 1.0540x over previous
//
#include <hip/hip_runtime.h>
#include <cstdint>

#define N_NODES 100000
#define N_EDGES 1600000
#define NBUCKET 196          // ceil(N_NODES / 512)
#define NPB_SHIFT 9
#define NPB 512              // nodes per bucket
#define P1_CHUNK 4096        // edges per partition block
#define NB_P1 391            // ceil(N_EDGES / P1_CHUNK)
#define NBG 1563             // gemm blocks (64 rows each)
#define PAD_RESERVE (NPB * 8)                 // worst-case per-bucket padding
#define NSLOT (N_EDGES + NBUCKET * PAD_RESERVE)   // 2,402,816 padded csr slots

typedef int iv4 __attribute__((ext_vector_type(4)));
typedef unsigned short usv8 __attribute__((ext_vector_type(8)));

__device__ __forceinline__ unsigned short f2bf(float x) {   // RNE f32->bf16
    unsigned u = __float_as_uint(x);
    unsigned r = ((u >> 16) & 1u) + 0x7FFFu;
    return (unsigned short)((u + r) >> 16);
}
__device__ __forceinline__ float bf2f(unsigned short v) {
    return __uint_as_float((unsigned)v << 16);
}

// ---------------- bucketed CSR build (no global data atomics) ----------------

__global__ __launch_bounds__(256) void k_p0(const int* __restrict__ dst,
                                            int* __restrict__ btot) {
    __shared__ int bcnt[NBUCKET];
    int t = threadIdx.x;
    for (int i = t; i < NBUCKET; i += 256) bcnt[i] = 0;
    __syncthreads();
    int e0 = blockIdx.x * P1_CHUNK;
#pragma unroll
    for (int i = 0; i < 4; ++i) {
        int idx = e0 + (t + i * 256) * 4;
        if (idx + 3 < N_EDGES) {
            int4 d = *reinterpret_cast<const int4*>(&dst[idx]);
            atomicAdd(&bcnt[d.x >> NPB_SHIFT], 1);
            atomicAdd(&bcnt[d.y >> NPB_SHIFT], 1);
            atomicAdd(&bcnt[d.z >> NPB_SHIFT], 1);
            atomicAdd(&bcnt[d.w >> NPB_SHIFT], 1);
        }
    }
    __syncthreads();
    for (int i = t; i < NBUCKET; i += 256)
        if (bcnt[i]) atomicAdd(&btot[i], bcnt[i]);
}

__global__ __launch_bounds__(256) void k_bscan(const int* __restrict__ btot,
                                               int* __restrict__ seg_base,
                                               int* __restrict__ gcursor) {
    __shared__ int tmp[256];
    int t = threadIdx.x;
    int v = (t < NBUCKET) ? btot[t] : 0;
    tmp[t] = v;
    __syncthreads();
    for (int off = 1; off < 256; off <<= 1) {
        int u = (t >= off) ? tmp[t - off] : 0;
        __syncthreads();
        tmp[t] += u;
        __syncthreads();
    }
    if (t < NBUCKET) { int ex = tmp[t] - v; seg_base[t] = ex; gcursor[t] = ex; }
    if (t == 0) seg_base[NBUCKET] = N_EDGES;
}

struct P1Shared {
    uint2 stage[P1_CHUNK];
    int cnt[256];
    int lbase[256];
    int gbase[256];
};
struct GemmShared { float sX[64][65]; float sW[64][65]; };

// P1: partition edges into bucket-ordered beidx (coalesced), fused with gemm1
__global__ __launch_bounds__(256) void k_p1gemm(const int* __restrict__ dst,
                                                int* gcursor,
                                                unsigned int* __restrict__ beidx,
                                                const float* __restrict__ X,
                                                const float* __restrict__ W,
                                                float* __restrict__ Y) {
    __shared__ union { P1Shared p; GemmShared g; } sm;
    int t = threadIdx.x;
    if (blockIdx.x < NB_P1) {
        for (int i = t; i < 256; i += 256) sm.p.cnt[i] = 0;
        __syncthreads();
        int e0 = blockIdx.x * P1_CHUNK;
        unsigned int dr[16];                       // (d<<12)|rank
#pragma unroll
        for (int i = 0; i < 4; ++i) {
            int idx = e0 + (t + i * 256) * 4;
            if (idx + 3 < N_EDGES) {
                int4 d4 = *reinterpret_cast<const int4*>(&dst[idx]);
                int r0 = atomicAdd(&sm.p.cnt[d4.x >> NPB_SHIFT], 1);
                int r1 = atomicAdd(&sm.p.cnt[d4.y >> NPB_SHIFT], 1);
                int r2 = atomicAdd(&sm.p.cnt[d4.z >> NPB_SHIFT], 1);
                int r3 = atomicAdd(&sm.p.cnt[d4.w >> NPB_SHIFT], 1);
                dr[i * 4 + 0] = ((unsigned)d4.x << 12) | (unsigned)r0;
                dr[i * 4 + 1] = ((unsigned)d4.y << 12) | (unsigned)r1;
                dr[i * 4 + 2] = ((unsigned)d4.z << 12) | (unsigned)r2;
                dr[i * 4 + 3] = ((unsigned)d4.w << 12) | (unsigned)r3;
            } else {
#pragma unroll
                for (int k = 0; k < 4; ++k) dr[i * 4 + k] = 0xFFFFFFFFu;
            }
        }
        __syncthreads();
        int v = sm.p.cnt[t];
        sm.p.lbase[t] = v;
        __syncthreads();
        for (int off = 1; off < 256; off <<= 1) {
            int u = (t >= off) ? sm.p.lbase[t - off] : 0;
            __syncthreads();
            sm.p.lbase[t] += u;
            __syncthreads();
        }
        int ex = sm.p.lbase[t] - v;
        if (t < NBUCKET) sm.p.gbase[t] = atomicAdd(&gcursor[t], v);
        __syncthreads();
        sm.p.lbase[t] = ex;
        __syncthreads();
#pragma unroll
        for (int j = 0; j < 16; ++j) {
            if (dr[j] != 0xFFFFFFFFu) {
                int d = dr[j] >> 12, r = dr[j] & 0xFFF, b = d >> NPB_SHIFT;
                int eid = e0 + ((t + (j >> 2) * 256) << 2) + (j & 3);
                sm.p.stage[sm.p.lbase[b] + r] = make_uint2((unsigned)d, (unsigned)eid);
            }
        }
        __syncthreads();
        int n_valid = min(P1_CHUNK, N_EDGES - e0);
        for (int j = t; j < n_valid; j += 256) {
            uint2 de = sm.p.stage[j];
            int b = (int)(de.x >> NPB_SHIFT);
            int pos = sm.p.gbase[b] + (j - sm.p.lbase[b]);
            beidx[pos] = ((de.x & (NPB - 1u)) << 21) | de.y;
        }
        return;
    }
    // ---- gemm1: Y = X @ W (f32 out; dinv not known yet) ----
    int rb = (blockIdx.x - NB_P1) * 64;
#pragma unroll
    for (int i = 0; i < 16; ++i) {
        int idx = t + i * 256;
        int r = idx >> 6, c = idx & 63;
        sm.g.sW[r][c] = W[idx];
        int gr = rb + r;
        sm.g.sX[r][c] = (gr < N_NODES) ? X[(size_t)gr * 64 + c] : 0.0f;
    }
    __syncthreads();
    int tr = (t >> 4) * 4;
    int tc = (t & 15) * 4;
    float acc[4][4] = {{0.f}};
#pragma unroll 8
    for (int k = 0; k < 64; ++k) {
        float xv[4], wv[4];
#pragma unroll
        for (int i = 0; i < 4; ++i) xv[i] = sm.g.sX[tr + i][k];
#pragma unroll
        for (int j = 0; j < 4; ++j) wv[j] = sm.g.sW[k][tc + j];
#pragma unroll
        for (int i = 0; i < 4; ++i)
#pragma unroll
            for (int j = 0; j < 4; ++j) acc[i][j] = fmaf(xv[i], wv[j], acc[i][j]);
    }
#pragma unroll
    for (int i = 0; i < 4; ++i) {
        int gr = rb + tr + i;
        if (gr < N_NODES) {
            float4 v = make_float4(acc[i][0], acc[i][1], acc[i][2], acc[i][3]);
            *reinterpret_cast<float4*>(&Y[(size_t)gr * 64 + tc]) = v;
        }
    }
}

// P2: per-bucket LDS hist+scan -> PADDED csr rows (mult of 8, raw w), rowinfo, dinv
__global__ __launch_bounds__(1024) void k_p2(const unsigned int* __restrict__ beidx,
                                             const int* __restrict__ seg_base,
                                             const int* __restrict__ srcarr,
                                             const float* __restrict__ ea,
                                             int* __restrict__ rank_g,
                                             int2* __restrict__ rowinfo,
                                             int2* __restrict__ csr,
                                             float* __restrict__ dinv) {
    __shared__ int cnt[NPB];
    __shared__ int prp[NPB];
    __shared__ float degw[NPB];
    __shared__ int stot;
    int t = threadIdx.x;
    int b = blockIdx.x;
    if (t < NPB) { cnt[t] = 0; degw[t] = 0.0f; }
    __syncthreads();
    int segb = seg_base[b], sege = seg_base[b + 1];
    int pbase = segb + b * PAD_RESERVE;
    for (int j = segb + t; j < sege; j += 1024) {
        rank_g[j] = atomicAdd(&cnt[beidx[j] >> 21], 1);
    }
    __syncthreads();
    int raw = (t < NPB) ? cnt[t] : 0;
    int pad = (raw + 7) & ~7;
    if (t < NPB) prp[t] = pad;
    __syncthreads();
    for (int off = 1; off < NPB; off <<= 1) {
        int u = (t >= off && t < NPB) ? prp[t - off] : 0;
        __syncthreads();
        if (t < NPB) prp[t] += u;
        __syncthreads();
    }
    if (t == NPB - 1) stot = prp[t];
    if (t < NPB) prp[t] -= pad;               // exclusive
    __syncthreads();
    int node = (b << NPB_SHIFT) + t;
    if (t < NPB && node < N_NODES)
        rowinfo[node] = make_int2(pbase + prp[t], pad >> 3);
    for (int j = segb + t; j < sege; j += 1024) {
        unsigned int v = beidx[j];
        int dloc = (int)(v >> 21);
        int eid = (int)(v & 0x1FFFFFu);
        int r = rank_g[j];
        float tt = ea[eid] * (1.0f / 200.0f);
        float w = __expf(-tt * tt);
        csr[pbase + prp[dloc] + r] = make_int2(srcarr[eid], __float_as_int(w));
        atomicAdd(&degw[dloc], w);
    }
    __syncthreads();
    if (t < NPB && node < N_NODES) {
        dinv[node] = rsqrtf(1.0f + degw[t]);
        int begin = pbase + prp[t];
        for (int j = raw; j < pad; ++j) csr[begin + j] = make_int2(node, 0);
    }
    int rawsz = sege - segb;
    for (int j = stot + t; j < rawsz + PAD_RESERVE; j += 1024)
        csr[pbase + j] = make_int2(0, 0);
}

// XWs[i,f] = bf16(dinv[i] * XW[i,f])  — scale+convert stream (8 elems/thread)
__global__ __launch_bounds__(256) void k_scale(const float* __restrict__ XW,
                                               const float* __restrict__ dinv,
                                               unsigned short* __restrict__ XWs) {
    int g = blockIdx.x * 256 + threadIdx.x;
    int base = g * 8;
    if (base >= N_NODES * 64) return;
    float d = dinv[base >> 6];
    float4 v0 = *reinterpret_cast<const float4*>(XW + base);
    float4 v1 = *reinterpret_cast<const float4*>(XW + base + 4);
    usv8 r;
    r.s0 = f2bf(d * v0.x); r.s1 = f2bf(d * v0.y);
    r.s2 = f2bf(d * v0.z); r.s3 = f2bf(d * v0.w);
    r.s4 = f2bf(d * v1.x); r.s5 = f2bf(d * v1.y);
    r.s6 = f2bf(d * v1.z); r.s7 = f2bf(d * v1.w);
    *reinterpret_cast<usv8*>(XWs + base) = r;
}

// ---------------- dense compute ----------------

// gemm2: Y = X @ W with epilogue  XWs[gr,:] = bf16(dinv[gr] * Y[gr,:])
__global__ __launch_bounds__(256) void k_gemm64s(const float* __restrict__ X,
                                                 const float* __restrict__ W,
                                                 const float* __restrict__ dinv,
                                                 unsigned short* __restrict__ XWs) {
    __shared__ float sX[64][65];
    __shared__ float sW[64][65];
    int t = threadIdx.x;
    int rb = blockIdx.x * 64;
#pragma unroll
    for (int i = 0; i < 16; ++i) {
        int idx = t + i * 256;
        int r = idx >> 6, c = idx & 63;
        sW[r][c] = W[idx];
        int gr = rb + r;
        sX[r][c] = (gr < N_NODES) ? X[(size_t)gr * 64 + c] : 0.0f;
    }
    __syncthreads();
    int tr = (t >> 4) * 4;
    int tc = (t & 15) * 4;
    float acc[4][4] = {{0.f}};
#pragma unroll 8
    for (int k = 0; k < 64; ++k) {
        float xv[4], wv[4];
#pragma unroll
        for (int i = 0; i < 4; ++i) xv[i] = sX[tr + i][k];
#pragma unroll
        for (int j = 0; j < 4; ++j) wv[j] = sW[k][tc + j];
#pragma unroll
        for (int i = 0; i < 4; ++i)
#pragma unroll
            for (int j = 0; j < 4; ++j) acc[i][j] = fmaf(xv[i], wv[j], acc[i][j]);
    }
#pragma unroll
    for (int i = 0; i < 4; ++i) {
        int gr = rb + tr + i;
        if (gr < N_NODES) {
            float d = dinv[gr];
            ushort4 v;
            v.x = f2bf(d * acc[i][0]); v.y = f2bf(d * acc[i][1]);
            v.z = f2bf(d * acc[i][2]); v.w = f2bf(d * acc[i][3]);
            *reinterpret_cast<ushort4*>(&XWs[((unsigned)gr << 6) + tc]) = v;
        }
    }
}

// one wave per node, lane = feature. bf16 scaled gather table, raw w in csr.
// MODE 0: OUT[i,f] = relu(di*(selfs+esum) + bias)          (f32 row out)
// MODE 1: h = relu(...); OUT[i] = di * dot(h, W3)          (scalar xw3s out)
template <int MODE>
__global__ __launch_bounds__(256) void k_agg64(const unsigned short* __restrict__ XWs,
                                               const int2* __restrict__ csr,
                                               const int2* __restrict__ rowinfo,
                                               const float* __restrict__ dinv,
                                               const float* __restrict__ bias,
                                               float* __restrict__ OUT,
                                               const float* __restrict__ W3) {
    int wid = (blockIdx.x * 256 + threadIdx.x) >> 6;
    unsigned f = threadIdx.x & 63;
    if (wid >= N_NODES) return;
    float di = dinv[wid];
    float selfs = bf2f(XWs[((unsigned)wid << 6) + f]);
    int2 ri = rowinfo[wid];
    const iv4* p = reinterpret_cast<const iv4*>(csr + ri.x);
    int nb = ri.y;
    float a[8] = {0.f, 0.f, 0.f, 0.f, 0.f, 0.f, 0.f, 0.f};
    for (int it = 0; it < nb; ++it, p += 4) {
        iv4 q0 = __builtin_nontemporal_load(p);
        iv4 q1 = __builtin_nontemporal_load(p + 1);
        iv4 q2 = __builtin_nontemporal_load(p + 2);
        iv4 q3 = __builtin_nontemporal_load(p + 3);
        float r0 = bf2f(XWs[((unsigned)q0.x << 6) + f]);
        float r1 = bf2f(XWs[((unsigned)q0.z << 6) + f]);
        float r2 = bf2f(XWs[((unsigned)q1.x << 6) + f]);
        float r3 = bf2f(XWs[((unsigned)q1.z << 6) + f]);
        float r4 = bf2f(XWs[((unsigned)q2.x << 6) + f]);
        float r5 = bf2f(XWs[((unsigned)q2.z << 6) + f]);
        float r6 = bf2f(XWs[((unsigned)q3.x << 6) + f]);
        float r7 = bf2f(XWs[((unsigned)q3.z << 6) + f]);
        a[0] = fmaf(__int_as_float(q0.y), r0, a[0]);
        a[1] = fmaf(__int_as_float(q0.w), r1, a[1]);
        a[2] = fmaf(__int_as_float(q1.y), r2, a[2]);
        a[3] = fmaf(__int_as_float(q1.w), r3, a[3]);
        a[4] = fmaf(__int_as_float(q2.y), r4, a[4]);
        a[5] = fmaf(__int_as_float(q2.w), r5, a[5]);
        a[6] = fmaf(__int_as_float(q3.y), r6, a[6]);
        a[7] = fmaf(__int_as_float(q3.w), r7, a[7]);
    }
    float esum = ((a[0] + a[1]) + (a[2] + a[3])) + ((a[4] + a[5]) + (a[6] + a[7]));
    float acc = di * (selfs + esum) + bias[f];
    acc = fmaxf(acc, 0.0f);
    if (MODE == 0) {
        OUT[((unsigned)wid << 6) + f] = acc;
    } else {
        float v = acc * W3[f];
#pragma unroll
        for (int off = 32; off > 0; off >>= 1) v += __shfl_down(v, off, 64);
        if (f == 0) OUT[wid] = di * v;          // store xw3s = dinv * xw3
    }
}

// out[i] = b3 + di*(xw3s[i] + sum_e w_e*xw3s[src_e])   (raw w, scaled table)
__global__ __launch_bounds__(256) void k_agg_scalar(const float* __restrict__ xw3s,
                                                    const int2* __restrict__ csr,
                                                    const int2* __restrict__ rowinfo,
                                                    const float* __restrict__ dinv,
                                                    const float* __restrict__ b3,
                                                    float* __restrict__ out) {
    int i = blockIdx.x * 256 + threadIdx.x;
    if (i >= N_NODES) return;
    float di = dinv[i];
    int2 ri = rowinfo[i];
    const iv4* p = reinterpret_cast<const iv4*>(csr + ri.x);
    int nb = ri.y;
    float a0 = 0.f, a1 = 0.f, a2 = 0.f, a3 = 0.f;
    for (int it = 0; it < nb; ++it, p += 4) {
        iv4 q0 = __builtin_nontemporal_load(p);
        iv4 q1 = __builtin_nontemporal_load(p + 1);
        iv4 q2 = __builtin_nontemporal_load(p + 2);
        iv4 q3 = __builtin_nontemporal_load(p + 3);
        a0 = fmaf(__int_as_float(q0.y), xw3s[q0.x], a0);
        a1 = fmaf(__int_as_float(q0.w), xw3s[q0.z], a1);
        a2 = fmaf(__int_as_float(q1.y), xw3s[q1.x], a2);
        a3 = fmaf(__int_as_float(q1.w), xw3s[q1.z], a3);
        a0 = fmaf(__int_as_float(q2.y), xw3s[q2.x], a0);
        a1 = fmaf(__int_as_float(q2.w), xw3s[q2.z], a1);
        a2 = fmaf(__int_as_float(q3.y), xw3s[q3.x], a2);
        a3 = fmaf(__int_as_float(q3.w), xw3s[q3.z], a3);
    }
    out[i] = di * (xw3s[i] + (a0 + a1) + (a2 + a3)) + b3[0];
}

// ---------------- launch ----------------

extern "C" void kernel_launch(void* const* d_in, const int* in_sizes, int n_in,
                              void* d_out, int out_size, void* d_ws, size_t ws_size,
                              hipStream_t stream) {
    const float* x  = (const float*)d_in[0];
    const int*   ei = (const int*)d_in[1];     // int32 per harness contract
    const float* ea = (const float*)d_in[2];
    const float* W1 = (const float*)d_in[3];
    const float* b1 = (const float*)d_in[4];
    const float* W2 = (const float*)d_in[5];
    const float* b2 = (const float*)d_in[6];
    const float* W3 = (const float*)d_in[7];
    const float* b3 = (const float*)d_in[8];
    float* out = (float*)d_out;
    const int* srcarr = ei;
    const int* dstarr = ei + N_EDGES;

    char* ws = (char*)d_ws;
    size_t off = 0;
    auto alloc = [&](size_t bytes) -> void* {
        void* p = ws + off;
        off = (off + bytes + 255) & ~(size_t)255;
        return p;
    };
    float* dinv     = (float*)alloc((size_t)N_NODES * 4);
    int2*  rowinfo  = (int2*) alloc((size_t)N_NODES * 8);
    int*   btot     = (int*)  alloc(NBUCKET * 4);
    int*   seg_base = (int*)  alloc((NBUCKET + 1) * 4);
    int*   gcursor  = (int*)  alloc(NBUCKET * 4);
    float* xw3s     = (float*)alloc((size_t)N_NODES * 4);
    // beidx (uint, 6.4 MB; dead after P2) shares a 12.8 MB region with XWs1
    void*  region   = alloc((size_t)N_NODES * 64 * 2);
    unsigned int*   beidx = (unsigned int*)region;
    unsigned short* XWs1  = (unsigned short*)region;
    int2*  csr      = (int2*) alloc((size_t)NSLOT * 8);
    float* bufA     = (float*)alloc((size_t)N_NODES * 64 * 4);   // gemm1 out f32; reused as XWs2
    float* bufB     = (float*)alloc((size_t)N_NODES * 64 * 4);
    unsigned short* XWs2 = (unsigned short*)bufA;  // bufA dead after k_scale reads it
    int*   rank_g   = (int*)bufB;   // bufB's first real write (agg1) is after P2

    const int nbW = N_NODES / 4;             // 25000
    const int nbN = (N_NODES + 255) / 256;   // 391
    const int nbS = (N_NODES * 64 / 8 + 255) / 256;   // 3125 scale blocks

    hipMemsetAsync(btot, 0, NBUCKET * 4, stream);
    k_p0<<<NB_P1, 256, 0, stream>>>(dstarr, btot);
    k_bscan<<<1, 256, 0, stream>>>(btot, seg_base, gcursor);
    k_p1gemm<<<NB_P1 + NBG, 256, 0, stream>>>(dstarr, gcursor, beidx, x, W1, bufA);
    k_p2<<<NBUCKET, 1024, 0, stream>>>(beidx, seg_base, srcarr, ea,
                                       rank_g, rowinfo, csr, dinv);
    k_scale<<<nbS, 256, 0, stream>>>(bufA, dinv, XWs1);   // overwrites beidx region

    k_agg64<0><<<nbW, 256, 0, stream>>>(XWs1, csr, rowinfo, dinv, b1, bufB, nullptr);
    k_gemm64s<<<NBG, 256, 0, stream>>>(bufB, W2, dinv, XWs2);   // overwrites bufA
    k_agg64<1><<<nbW, 256, 0, stream>>>(XWs2, csr, rowinfo, dinv, b2, xw3s, W3);
    k_agg_scalar<<<nbN, 256, 0, stream>>>(xw3s, csr, rowinfo, dinv, b3, out);
}

// Round 10
// 244.380 us; speedup vs baseline: 2.5276x; 1.2125x over previous
//
#include <hip/hip_runtime.h>
#include <cstdint>

#define N_NODES 100000
#define N_EDGES 1600000
#define NBUCKET 196          // ceil(N_NODES / 512)
#define NPB_SHIFT 9
#define NPB 512              // nodes per bucket
#define P1_CHUNK 4096        // edges per partition block
#define NB_P1 391            // ceil(N_EDGES / P1_CHUNK)
#define NBG 1563             // gemm blocks (64 rows each)
#define PAD_RESERVE (NPB * 8)                 // worst-case per-bucket padding
#define NSLOT (N_EDGES + NBUCKET * PAD_RESERVE)   // 2,402,816 padded csr slots

typedef int iv4 __attribute__((ext_vector_type(4)));
typedef unsigned short usv8 __attribute__((ext_vector_type(8)));

__device__ __forceinline__ unsigned short f2bf(float x) {   // RNE f32->bf16
    unsigned u = __float_as_uint(x);
    unsigned r = ((u >> 16) & 1u) + 0x7FFFu;
    return (unsigned short)((u + r) >> 16);
}
__device__ __forceinline__ float bf2f(unsigned short v) {
    return __uint_as_float((unsigned)v << 16);
}

// ---------------- bucketed CSR build (no global data atomics) ----------------

__global__ __launch_bounds__(256) void k_p0(const int* __restrict__ dst,
                                            int* __restrict__ btot) {
    __shared__ int bcnt[NBUCKET];
    int t = threadIdx.x;
    for (int i = t; i < NBUCKET; i += 256) bcnt[i] = 0;
    __syncthreads();
    int e0 = blockIdx.x * P1_CHUNK;
#pragma unroll
    for (int i = 0; i < 4; ++i) {
        int idx = e0 + (t + i * 256) * 4;
        if (idx + 3 < N_EDGES) {
            int4 d = *reinterpret_cast<const int4*>(&dst[idx]);
            atomicAdd(&bcnt[d.x >> NPB_SHIFT], 1);
            atomicAdd(&bcnt[d.y >> NPB_SHIFT], 1);
            atomicAdd(&bcnt[d.z >> NPB_SHIFT], 1);
            atomicAdd(&bcnt[d.w >> NPB_SHIFT], 1);
        }
    }
    __syncthreads();
    for (int i = t; i < NBUCKET; i += 256)
        if (bcnt[i]) atomicAdd(&btot[i], bcnt[i]);
}

__global__ __launch_bounds__(256) void k_bscan(const int* __restrict__ btot,
                                               int* __restrict__ seg_base,
                                               int* __restrict__ gcursor) {
    __shared__ int tmp[256];
    int t = threadIdx.x;
    int v = (t < NBUCKET) ? btot[t] : 0;
    tmp[t] = v;
    __syncthreads();
    for (int off = 1; off < 256; off <<= 1) {
        int u = (t >= off) ? tmp[t - off] : 0;
        __syncthreads();
        tmp[t] += u;
        __syncthreads();
    }
    if (t < NBUCKET) { int ex = tmp[t] - v; seg_base[t] = ex; gcursor[t] = ex; }
    if (t == 0) seg_base[NBUCKET] = N_EDGES;
}

struct P1Shared {
    uint2 stage[P1_CHUNK];
    int cnt[256];
    int lbase[256];
    int gbase[256];
};
struct GemmShared { float sX[64][65]; float sW[64][65]; };

// P1: partition edges into bucket-ordered beidx (coalesced), fused with gemm1
__global__ __launch_bounds__(256) void k_p1gemm(const int* __restrict__ dst,
                                                int* gcursor,
                                                unsigned int* __restrict__ beidx,
                                                const float* __restrict__ X,
                                                const float* __restrict__ W,
                                                float* __restrict__ Y) {
    __shared__ union { P1Shared p; GemmShared g; } sm;
    int t = threadIdx.x;
    if (blockIdx.x < NB_P1) {
        for (int i = t; i < 256; i += 256) sm.p.cnt[i] = 0;
        __syncthreads();
        int e0 = blockIdx.x * P1_CHUNK;
        unsigned int dr[16];                       // (d<<12)|rank
#pragma unroll
        for (int i = 0; i < 4; ++i) {
            int idx = e0 + (t + i * 256) * 4;
            if (idx + 3 < N_EDGES) {
                int4 d4 = *reinterpret_cast<const int4*>(&dst[idx]);
                int r0 = atomicAdd(&sm.p.cnt[d4.x >> NPB_SHIFT], 1);
                int r1 = atomicAdd(&sm.p.cnt[d4.y >> NPB_SHIFT], 1);
                int r2 = atomicAdd(&sm.p.cnt[d4.z >> NPB_SHIFT], 1);
                int r3 = atomicAdd(&sm.p.cnt[d4.w >> NPB_SHIFT], 1);
                dr[i * 4 + 0] = ((unsigned)d4.x << 12) | (unsigned)r0;
                dr[i * 4 + 1] = ((unsigned)d4.y << 12) | (unsigned)r1;
                dr[i * 4 + 2] = ((unsigned)d4.z << 12) | (unsigned)r2;
                dr[i * 4 + 3] = ((unsigned)d4.w << 12) | (unsigned)r3;
            } else {
#pragma unroll
                for (int k = 0; k < 4; ++k) dr[i * 4 + k] = 0xFFFFFFFFu;
            }
        }
        __syncthreads();
        int v = sm.p.cnt[t];
        sm.p.lbase[t] = v;
        __syncthreads();
        for (int off = 1; off < 256; off <<= 1) {
            int u = (t >= off) ? sm.p.lbase[t - off] : 0;
            __syncthreads();
            sm.p.lbase[t] += u;
            __syncthreads();
        }
        int ex = sm.p.lbase[t] - v;
        if (t < NBUCKET) sm.p.gbase[t] = atomicAdd(&gcursor[t], v);
        __syncthreads();
        sm.p.lbase[t] = ex;
        __syncthreads();
#pragma unroll
        for (int j = 0; j < 16; ++j) {
            if (dr[j] != 0xFFFFFFFFu) {
                int d = dr[j] >> 12, r = dr[j] & 0xFFF, b = d >> NPB_SHIFT;
                int eid = e0 + ((t + (j >> 2) * 256) << 2) + (j & 3);
                sm.p.stage[sm.p.lbase[b] + r] = make_uint2((unsigned)d, (unsigned)eid);
            }
        }
        __syncthreads();
        int n_valid = min(P1_CHUNK, N_EDGES - e0);
        for (int j = t; j < n_valid; j += 256) {
            uint2 de = sm.p.stage[j];
            int b = (int)(de.x >> NPB_SHIFT);
            int pos = sm.p.gbase[b] + (j - sm.p.lbase[b]);
            beidx[pos] = ((de.x & (NPB - 1u)) << 21) | de.y;
        }
        return;
    }
    // ---- gemm1: Y = X @ W (f32 out; dinv not known yet) ----
    int rb = (blockIdx.x - NB_P1) * 64;
#pragma unroll
    for (int i = 0; i < 16; ++i) {
        int idx = t + i * 256;
        int r = idx >> 6, c = idx & 63;
        sm.g.sW[r][c] = W[idx];
        int gr = rb + r;
        sm.g.sX[r][c] = (gr < N_NODES) ? X[(size_t)gr * 64 + c] : 0.0f;
    }
    __syncthreads();
    int tr = (t >> 4) * 4;
    int tc = (t & 15) * 4;
    float acc[4][4] = {{0.f}};
#pragma unroll 8
    for (int k = 0; k < 64; ++k) {
        float xv[4], wv[4];
#pragma unroll
        for (int i = 0; i < 4; ++i) xv[i] = sm.g.sX[tr + i][k];
#pragma unroll
        for (int j = 0; j < 4; ++j) wv[j] = sm.g.sW[k][tc + j];
#pragma unroll
        for (int i = 0; i < 4; ++i)
#pragma unroll
            for (int j = 0; j < 4; ++j) acc[i][j] = fmaf(xv[i], wv[j], acc[i][j]);
    }
#pragma unroll
    for (int i = 0; i < 4; ++i) {
        int gr = rb + tr + i;
        if (gr < N_NODES) {
            float4 v = make_float4(acc[i][0], acc[i][1], acc[i][2], acc[i][3]);
            *reinterpret_cast<float4*>(&Y[(size_t)gr * 64 + tc]) = v;
        }
    }
}

// P2: per-bucket LDS hist+scan -> PADDED csr rows (mult of 8, raw w), rowinfo, dinv
__global__ __launch_bounds__(1024) void k_p2(const unsigned int* __restrict__ beidx,
                                             const int* __restrict__ seg_base,
                                             const int* __restrict__ srcarr,
                                             const float* __restrict__ ea,
                                             int* __restrict__ rank_g,
                                             int2* __restrict__ rowinfo,
                                             int2* __restrict__ csr,
                                             float* __restrict__ dinv) {
    __shared__ int cnt[NPB];
    __shared__ int prp[NPB];
    __shared__ float degw[NPB];
    __shared__ int stot;
    int t = threadIdx.x;
    int b = blockIdx.x;
    if (t < NPB) { cnt[t] = 0; degw[t] = 0.0f; }
    __syncthreads();
    int segb = seg_base[b], sege = seg_base[b + 1];
    int pbase = segb + b * PAD_RESERVE;
    for (int j = segb + t; j < sege; j += 1024) {
        rank_g[j] = atomicAdd(&cnt[beidx[j] >> 21], 1);
    }
    __syncthreads();
    int raw = (t < NPB) ? cnt[t] : 0;
    int pad = (raw + 7) & ~7;
    if (t < NPB) prp[t] = pad;
    __syncthreads();
    for (int off = 1; off < NPB; off <<= 1) {
        int u = (t >= off && t < NPB) ? prp[t - off] : 0;
        __syncthreads();
        if (t < NPB) prp[t] += u;
        __syncthreads();
    }
    if (t == NPB - 1) stot = prp[t];
    if (t < NPB) prp[t] -= pad;               // exclusive
    __syncthreads();
    int node = (b << NPB_SHIFT) + t;
    if (t < NPB && node < N_NODES)
        rowinfo[node] = make_int2(pbase + prp[t], pad >> 3);
    for (int j = segb + t; j < sege; j += 1024) {
        unsigned int v = beidx[j];
        int dloc = (int)(v >> 21);
        int eid = (int)(v & 0x1FFFFFu);
        int r = rank_g[j];
        float tt = ea[eid] * (1.0f / 200.0f);
        float w = __expf(-tt * tt);
        csr[pbase + prp[dloc] + r] = make_int2(srcarr[eid], __float_as_int(w));
        atomicAdd(&degw[dloc], w);
    }
    __syncthreads();
    if (t < NPB && node < N_NODES) {
        dinv[node] = rsqrtf(1.0f + degw[t]);
        int begin = pbase + prp[t];
        for (int j = raw; j < pad; ++j) csr[begin + j] = make_int2(node, 0);
    }
    int rawsz = sege - segb;
    for (int j = stot + t; j < rawsz + PAD_RESERVE; j += 1024)
        csr[pbase + j] = make_int2(0, 0);
}

// XWs[i,f] = bf16(dinv[i] * XW[i,f])  — scale+convert stream (8 elems/thread)
__global__ __launch_bounds__(256) void k_scale(const float* __restrict__ XW,
                                               const float* __restrict__ dinv,
                                               unsigned short* __restrict__ XWs) {
    int g = blockIdx.x * 256 + threadIdx.x;
    int base = g * 8;
    if (base >= N_NODES * 64) return;
    float d = dinv[base >> 6];
    float4 v0 = *reinterpret_cast<const float4*>(XW + base);
    float4 v1 = *reinterpret_cast<const float4*>(XW + base + 4);
    usv8 r;
    r.s0 = f2bf(d * v0.x); r.s1 = f2bf(d * v0.y);
    r.s2 = f2bf(d * v0.z); r.s3 = f2bf(d * v0.w);
    r.s4 = f2bf(d * v1.x); r.s5 = f2bf(d * v1.y);
    r.s6 = f2bf(d * v1.z); r.s7 = f2bf(d * v1.w);
    *reinterpret_cast<usv8*>(XWs + base) = r;
}

// ---------------- dense compute ----------------

// gemm2: Y = X @ W with epilogue  XWs[gr,:] = bf16(dinv[gr] * Y[gr,:])
__global__ __launch_bounds__(256) void k_gemm64s(const float* __restrict__ X,
                                                 const float* __restrict__ W,
                                                 const float* __restrict__ dinv,
                                                 unsigned short* __restrict__ XWs) {
    __shared__ float sX[64][65];
    __shared__ float sW[64][65];
    int t = threadIdx.x;
    int rb = blockIdx.x * 64;
#pragma unroll
    for (int i = 0; i < 16; ++i) {
        int idx = t + i * 256;
        int r = idx >> 6, c = idx & 63;
        sW[r][c] = W[idx];
        int gr = rb + r;
        sX[r][c] = (gr < N_NODES) ? X[(size_t)gr * 64 + c] : 0.0f;
    }
    __syncthreads();
    int tr = (t >> 4) * 4;
    int tc = (t & 15) * 4;
    float acc[4][4] = {{0.f}};
#pragma unroll 8
    for (int k = 0; k < 64; ++k) {
        float xv[4], wv[4];
#pragma unroll
        for (int i = 0; i < 4; ++i) xv[i] = sX[tr + i][k];
#pragma unroll
        for (int j = 0; j < 4; ++j) wv[j] = sW[k][tc + j];
#pragma unroll
        for (int i = 0; i < 4; ++i)
#pragma unroll
            for (int j = 0; j < 4; ++j) acc[i][j] = fmaf(xv[i], wv[j], acc[i][j]);
    }
#pragma unroll
    for (int i = 0; i < 4; ++i) {
        int gr = rb + tr + i;
        if (gr < N_NODES) {
            float d = dinv[gr];
            ushort4 v;
            v.x = f2bf(d * acc[i][0]); v.y = f2bf(d * acc[i][1]);
            v.z = f2bf(d * acc[i][2]); v.w = f2bf(d * acc[i][3]);
            *reinterpret_cast<ushort4*>(&XWs[((unsigned)gr << 6) + tc]) = v;
        }
    }
}

// one wave per node, lane = feature. CSR path fully SCALARIZED:
// readfirstlane forces wave-uniform base -> s_load through K$ (no vector-L1
// broadcast cost); edge (src,w) live in SGPRs, w feeds v_fmac as SGPR operand.
// MODE 0: OUT[i,f] = relu(di*(selfs+esum) + bias)          (f32 row out)
// MODE 1: h = relu(...); OUT[i] = di * dot(h, W3)          (scalar xw3s out)
template <int MODE>
__global__ __launch_bounds__(256) void k_agg64(const unsigned short* __restrict__ XWs,
                                               const int* __restrict__ csr_i,
                                               const int2* __restrict__ rowinfo,
                                               const float* __restrict__ dinv,
                                               const float* __restrict__ bias,
                                               float* __restrict__ OUT,
                                               const float* __restrict__ W3) {
    int wid0 = (blockIdx.x * 256 + threadIdx.x) >> 6;
    if (wid0 >= N_NODES) return;                     // wave-uniform exit
    int wid = __builtin_amdgcn_readfirstlane(wid0);  // explicit SGPR
    unsigned f = threadIdx.x & 63;
    float di = dinv[wid];                            // scalar load
    float selfs = bf2f(XWs[((unsigned)wid << 6) + f]);
    int2 ri = rowinfo[wid];                          // scalar load
    int rbase = __builtin_amdgcn_readfirstlane(ri.x);
    int nb    = __builtin_amdgcn_readfirstlane(ri.y);
    const int* pc = csr_i + ((size_t)rbase * 2);     // uniform pointer
    float a[8] = {0.f, 0.f, 0.f, 0.f, 0.f, 0.f, 0.f, 0.f};
    for (int it = 0; it < nb; ++it, pc += 16) {
        int s0 = pc[0],  w0 = pc[1],  s1 = pc[2],  w1 = pc[3];
        int s2 = pc[4],  w2 = pc[5],  s3 = pc[6],  w3 = pc[7];
        int s4 = pc[8],  w4 = pc[9],  s5 = pc[10], w5 = pc[11];
        int s6 = pc[12], w6 = pc[13], s7 = pc[14], w7 = pc[15];
        float r0 = bf2f(XWs[((unsigned)s0 << 6) + f]);
        float r1 = bf2f(XWs[((unsigned)s1 << 6) + f]);
        float r2 = bf2f(XWs[((unsigned)s2 << 6) + f]);
        float r3 = bf2f(XWs[((unsigned)s3 << 6) + f]);
        float r4 = bf2f(XWs[((unsigned)s4 << 6) + f]);
        float r5 = bf2f(XWs[((unsigned)s5 << 6) + f]);
        float r6 = bf2f(XWs[((unsigned)s6 << 6) + f]);
        float r7 = bf2f(XWs[((unsigned)s7 << 6) + f]);
        a[0] = fmaf(__int_as_float(w0), r0, a[0]);
        a[1] = fmaf(__int_as_float(w1), r1, a[1]);
        a[2] = fmaf(__int_as_float(w2), r2, a[2]);
        a[3] = fmaf(__int_as_float(w3), r3, a[3]);
        a[4] = fmaf(__int_as_float(w4), r4, a[4]);
        a[5] = fmaf(__int_as_float(w5), r5, a[5]);
        a[6] = fmaf(__int_as_float(w6), r6, a[6]);
        a[7] = fmaf(__int_as_float(w7), r7, a[7]);
    }
    float esum = ((a[0] + a[1]) + (a[2] + a[3])) + ((a[4] + a[5]) + (a[6] + a[7]));
    float acc = di * (selfs + esum) + bias[f];
    acc = fmaxf(acc, 0.0f);
    if (MODE == 0) {
        OUT[((unsigned)wid << 6) + f] = acc;
    } else {
        float v = acc * W3[f];
#pragma unroll
        for (int off = 32; off > 0; off >>= 1) v += __shfl_down(v, off, 64);
        if (f == 0) OUT[wid] = di * v;          // store xw3s = dinv * xw3
    }
}

// out[i] = b3 + di*(xw3s[i] + sum_e w_e*xw3s[src_e])   (raw w, scaled table)
__global__ __launch_bounds__(256) void k_agg_scalar(const float* __restrict__ xw3s,
                                                    const int2* __restrict__ csr,
                                                    const int2* __restrict__ rowinfo,
                                                    const float* __restrict__ dinv,
                                                    const float* __restrict__ b3,
                                                    float* __restrict__ out) {
    int i = blockIdx.x * 256 + threadIdx.x;
    if (i >= N_NODES) return;
    float di = dinv[i];
    int2 ri = rowinfo[i];
    const iv4* p = reinterpret_cast<const iv4*>(csr + ri.x);
    int nb = ri.y;
    float a0 = 0.f, a1 = 0.f, a2 = 0.f, a3 = 0.f;
    for (int it = 0; it < nb; ++it, p += 4) {
        iv4 q0 = __builtin_nontemporal_load(p);
        iv4 q1 = __builtin_nontemporal_load(p + 1);
        iv4 q2 = __builtin_nontemporal_load(p + 2);
        iv4 q3 = __builtin_nontemporal_load(p + 3);
        a0 = fmaf(__int_as_float(q0.y), xw3s[q0.x], a0);
        a1 = fmaf(__int_as_float(q0.w), xw3s[q0.z], a1);
        a2 = fmaf(__int_as_float(q1.y), xw3s[q1.x], a2);
        a3 = fmaf(__int_as_float(q1.w), xw3s[q1.z], a3);
        a0 = fmaf(__int_as_float(q2.y), xw3s[q2.x], a0);
        a1 = fmaf(__int_as_float(q2.w), xw3s[q2.z], a1);
        a2 = fmaf(__int_as_float(q3.y), xw3s[q3.x], a2);
        a3 = fmaf(__int_as_float(q3.w), xw3s[q3.z], a3);
    }
    out[i] = di * (xw3s[i] + (a0 + a1) + (a2 + a3)) + b3[0];
}

// ---------------- launch ----------------

extern "C" void kernel_launch(void* const* d_in, const int* in_sizes, int n_in,
                              void* d_out, int out_size, void* d_ws, size_t ws_size,
                              hipStream_t stream) {
    const float* x  = (const float*)d_in[0];
    const int*   ei = (const int*)d_in[1];     // int32 per harness contract
    const float* ea = (const float*)d_in[2];
    const float* W1 = (const float*)d_in[3];
    const float* b1 = (const float*)d_in[4];
    const float* W2 = (const float*)d_in[5];
    const float* b2 = (const float*)d_in[6];
    const float* W3 = (const float*)d_in[7];
    const float* b3 = (const float*)d_in[8];
    float* out = (float*)d_out;
    const int* srcarr = ei;
    const int* dstarr = ei + N_EDGES;

    char* ws = (char*)d_ws;
    size_t off = 0;
    auto alloc = [&](size_t bytes) -> void* {
        void* p = ws + off;
        off = (off + bytes + 255) & ~(size_t)255;
        return p;
    };
    float* dinv     = (float*)alloc((size_t)N_NODES * 4);
    int2*  rowinfo  = (int2*) alloc((size_t)N_NODES * 8);
    int*   btot     = (int*)  alloc(NBUCKET * 4);
    int*   seg_base = (int*)  alloc((NBUCKET + 1) * 4);
    int*   gcursor  = (int*)  alloc(NBUCKET * 4);
    float* xw3s     = (float*)alloc((size_t)N_NODES * 4);
    // beidx (uint, 6.4 MB; dead after P2) shares a 12.8 MB region with XWs1
    void*  region   = alloc((size_t)N_NODES * 64 * 2);
    unsigned int*   beidx = (unsigned int*)region;
    unsigned short* XWs1  = (unsigned short*)region;
    int2*  csr      = (int2*) alloc((size_t)NSLOT * 8);
    float* bufA     = (float*)alloc((size_t)N_NODES * 64 * 4);   // gemm1 out f32; reused as XWs2
    float* bufB     = (float*)alloc((size_t)N_NODES * 64 * 4);
    unsigned short* XWs2 = (unsigned short*)bufA;  // bufA dead after k_scale reads it
    int*   rank_g   = (int*)bufB;   // bufB's first real write (agg1) is after P2

    const int nbW = N_NODES / 4;             // 25000
    const int nbN = (N_NODES + 255) / 256;   // 391
    const int nbS = (N_NODES * 64 / 8 + 255) / 256;   // 3125 scale blocks

    hipMemsetAsync(btot, 0, NBUCKET * 4, stream);
    k_p0<<<NB_P1, 256, 0, stream>>>(dstarr, btot);
    k_bscan<<<1, 256, 0, stream>>>(btot, seg_base, gcursor);
    k_p1gemm<<<NB_P1 + NBG, 256, 0, stream>>>(dstarr, gcursor, beidx, x, W1, bufA);
    k_p2<<<NBUCKET, 1024, 0, stream>>>(beidx, seg_base, srcarr, ea,
                                       rank_g, rowinfo, csr, dinv);
    k_scale<<<nbS, 256, 0, stream>>>(bufA, dinv, XWs1);   // overwrites beidx region

    k_agg64<0><<<nbW, 256, 0, stream>>>(XWs1, (const int*)csr, rowinfo, dinv, b1, bufB, nullptr);
    k_gemm64s<<<NBG, 256, 0, stream>>>(bufB, W2, dinv, XWs2);   // overwrites bufA
    k_agg64<1><<<nbW, 256, 0, stream>>>(XWs2, (const int*)csr, rowinfo, dinv, b2, xw3s, W3);
    k_agg_scalar<<<nbN, 256, 0, stream>>>(xw3s, csr, rowinfo, dinv, b3, out);
}

// Round 11
// 206.885 us; speedup vs baseline: 2.9857x; 1.1812x over previous
//
#include <hip/hip_runtime.h>
#include <cstdint>

#define N_NODES 100000
#define N_EDGES 1600000
#define NBUCKET 196          // ceil(N_NODES / 512)
#define NPB_SHIFT 9
#define NPB 512              // nodes per bucket
#define P1_CHUNK 4096        // edges per partition block
#define NB_P1 391            // ceil(N_EDGES / P1_CHUNK)
#define NBG 1563             // gemm blocks (64 rows each)
#define BSW_CAP 9216         // per-bucket edge capacity (mean 8163, sigma~90)
#define CSR_CAP 12800        // per-bucket padded csr capacity (raw + 512*7 + slack)

typedef int iv4 __attribute__((ext_vector_type(4)));
typedef unsigned short usv8 __attribute__((ext_vector_type(8)));

__device__ __forceinline__ unsigned short f2bf(float x) {   // RNE f32->bf16
    unsigned u = __float_as_uint(x);
    unsigned r = ((u >> 16) & 1u) + 0x7FFFu;
    return (unsigned short)((u + r) >> 16);
}
__device__ __forceinline__ float bf2f(unsigned short v) {
    return __uint_as_float((unsigned)v << 16);
}

// ---------------- bucketed CSR build (no global data atomics) ----------------

// init per-bucket global cursors to static segment bases
__global__ __launch_bounds__(256) void k_init(int* __restrict__ gcursor) {
    int i = threadIdx.x;
    if (i < NBUCKET) gcursor[i] = i * BSW_CAP;
}

struct P1Shared {
    uint2 stage[P1_CHUNK];              // ((dloc<<17)|src, w) bucket-ordered   32 KB
    unsigned char stage_bkt[P1_CHUNK];  // bucket id per slot                    4 KB
    int cnt[256];
    int lbase[256];
    int gbase[256];
};
struct GemmShared { float sX[64][65]; float sW[64][65]; };

// P1: partition edges into bucket-ordered bsw=(dloc|src, w) with coalesced
// src/ea reads + exp computed here; fused with gemm1.
__global__ __launch_bounds__(256) void k_p1gemm(const int* __restrict__ dst,
                                                const int* __restrict__ srcarr,
                                                const float* __restrict__ ea,
                                                int* gcursor,
                                                uint2* __restrict__ bsw,
                                                const float* __restrict__ X,
                                                const float* __restrict__ W,
                                                float* __restrict__ Y) {
    __shared__ union { P1Shared p; GemmShared g; } sm;
    int t = threadIdx.x;
    if (blockIdx.x < NB_P1) {
        sm.p.cnt[t] = 0;
        __syncthreads();
        int e0 = blockIdx.x * P1_CHUNK;
        unsigned int dr[16];                       // (d<<12)|rank
#pragma unroll
        for (int i = 0; i < 4; ++i) {
            int idx = e0 + (t + i * 256) * 4;
            if (idx + 3 < N_EDGES) {
                int4 d4 = *reinterpret_cast<const int4*>(&dst[idx]);
                int r0 = atomicAdd(&sm.p.cnt[d4.x >> NPB_SHIFT], 1);
                int r1 = atomicAdd(&sm.p.cnt[d4.y >> NPB_SHIFT], 1);
                int r2 = atomicAdd(&sm.p.cnt[d4.z >> NPB_SHIFT], 1);
                int r3 = atomicAdd(&sm.p.cnt[d4.w >> NPB_SHIFT], 1);
                dr[i * 4 + 0] = ((unsigned)d4.x << 12) | (unsigned)r0;
                dr[i * 4 + 1] = ((unsigned)d4.y << 12) | (unsigned)r1;
                dr[i * 4 + 2] = ((unsigned)d4.z << 12) | (unsigned)r2;
                dr[i * 4 + 3] = ((unsigned)d4.w << 12) | (unsigned)r3;
            } else {
#pragma unroll
                for (int k = 0; k < 4; ++k) dr[i * 4 + k] = 0xFFFFFFFFu;
            }
        }
        __syncthreads();
        // exclusive scan of cnt -> lbase; reserve global bucket space
        int v = sm.p.cnt[t];
        sm.p.lbase[t] = v;
        __syncthreads();
        for (int off = 1; off < 256; off <<= 1) {
            int u = (t >= off) ? sm.p.lbase[t - off] : 0;
            __syncthreads();
            sm.p.lbase[t] += u;
            __syncthreads();
        }
        int ex = sm.p.lbase[t] - v;
        if (t < NBUCKET) sm.p.gbase[t] = atomicAdd(&gcursor[t], v);
        __syncthreads();
        sm.p.lbase[t] = ex;
        __syncthreads();
        // stage (dloc|src, w) bucket-sorted; coalesced src/ea reads, exp here
#pragma unroll
        for (int i = 0; i < 4; ++i) {
            int idx = e0 + (t + i * 256) * 4;
            if (idx + 3 < N_EDGES) {
                int4 s4 = *reinterpret_cast<const int4*>(&srcarr[idx]);
                float4 a4 = *reinterpret_cast<const float4*>(&ea[idx]);
                float t0 = a4.x * (1.0f / 200.0f), t1 = a4.y * (1.0f / 200.0f);
                float t2 = a4.z * (1.0f / 200.0f), t3 = a4.w * (1.0f / 200.0f);
                int   ss[4] = {s4.x, s4.y, s4.z, s4.w};
                float ww[4] = {__expf(-t0 * t0), __expf(-t1 * t1),
                               __expf(-t2 * t2), __expf(-t3 * t3)};
#pragma unroll
                for (int k = 0; k < 4; ++k) {
                    unsigned drv = dr[i * 4 + k];
                    int d = drv >> 12, r = drv & 0xFFF;
                    int b = d >> NPB_SHIFT, dloc = d & (NPB - 1);
                    int pos = sm.p.lbase[b] + r;
                    sm.p.stage[pos] = make_uint2(((unsigned)dloc << 17) | (unsigned)ss[k],
                                                 __float_as_uint(ww[k]));
                    sm.p.stage_bkt[pos] = (unsigned char)b;
                }
            }
        }
        __syncthreads();
        // stream out coalesced runs
        int n_valid = min(P1_CHUNK, N_EDGES - e0);
        for (int j = t; j < n_valid; j += 256) {
            int b = sm.p.stage_bkt[j];
            int pos = sm.p.gbase[b] + (j - sm.p.lbase[b]);
            bsw[pos] = sm.p.stage[j];
        }
        return;
    }
    // ---- gemm1: Y = X @ W (f32 out; dinv not known yet) ----
    int rb = (blockIdx.x - NB_P1) * 64;
#pragma unroll
    for (int i = 0; i < 16; ++i) {
        int idx = t + i * 256;
        int r = idx >> 6, c = idx & 63;
        sm.g.sW[r][c] = W[idx];
        int gr = rb + r;
        sm.g.sX[r][c] = (gr < N_NODES) ? X[(size_t)gr * 64 + c] : 0.0f;
    }
    __syncthreads();
    int tr = (t >> 4) * 4;
    int tc = (t & 15) * 4;
    float acc[4][4] = {{0.f}};
#pragma unroll 8
    for (int k = 0; k < 64; ++k) {
        float xv[4], wv[4];
#pragma unroll
        for (int i = 0; i < 4; ++i) xv[i] = sm.g.sX[tr + i][k];
#pragma unroll
        for (int j = 0; j < 4; ++j) wv[j] = sm.g.sW[k][tc + j];
#pragma unroll
        for (int i = 0; i < 4; ++i)
#pragma unroll
            for (int j = 0; j < 4; ++j) acc[i][j] = fmaf(xv[i], wv[j], acc[i][j]);
    }
#pragma unroll
    for (int i = 0; i < 4; ++i) {
        int gr = rb + tr + i;
        if (gr < N_NODES) {
            float4 v = make_float4(acc[i][0], acc[i][1], acc[i][2], acc[i][3]);
            *reinterpret_cast<float4*>(&Y[(size_t)gr * 64 + tc]) = v;
        }
    }
}

// P2: pure-streaming per-bucket build. LDS hist -> scan -> LDS-cursor scatter.
// No random global reads, no rank round-trip, no gap fill.
__global__ __launch_bounds__(1024) void k_p2(const uint2* __restrict__ bsw,
                                             const int* __restrict__ gcursor,
                                             int2* __restrict__ rowinfo,
                                             int2* __restrict__ csr,
                                             float* __restrict__ dinv) {
    __shared__ int cnt[NPB];
    __shared__ int prp[NPB];
    __shared__ int cur[NPB];
    __shared__ float degw[NPB];
    int t = threadIdx.x;
    int b = blockIdx.x;
    if (t < NPB) { cnt[t] = 0; degw[t] = 0.0f; }
    __syncthreads();
    int segb = b * BSW_CAP;
    int sege = gcursor[b];                 // = segb + bucket count
    int pbase = b * CSR_CAP;
    for (int j = segb + t; j < sege; j += 1024)
        atomicAdd(&cnt[bsw[j].x >> 17], 1);
    __syncthreads();
    int raw = (t < NPB) ? cnt[t] : 0;
    int pad = (raw + 7) & ~7;
    if (t < NPB) prp[t] = pad;
    __syncthreads();
    for (int off = 1; off < NPB; off <<= 1) {
        int u = (t >= off && t < NPB) ? prp[t - off] : 0;
        __syncthreads();
        if (t < NPB) prp[t] += u;
        __syncthreads();
    }
    if (t < NPB) { prp[t] -= pad; cur[t] = prp[t]; }   // exclusive base + cursor
    __syncthreads();
    int node = (b << NPB_SHIFT) + t;
    if (t < NPB && node < N_NODES)
        rowinfo[node] = make_int2(pbase + prp[t], pad >> 3);
    for (int j = segb + t; j < sege; j += 1024) {
        uint2 v = bsw[j];
        int dloc = (int)(v.x >> 17);
        int src  = (int)(v.x & 0x1FFFFu);
        int pos = atomicAdd(&cur[dloc], 1);
        csr[pbase + pos] = make_int2(src, (int)v.y);
        atomicAdd(&degw[dloc], __uint_as_float(v.y));
    }
    __syncthreads();
    if (t < NPB && node < N_NODES) {
        dinv[node] = rsqrtf(1.0f + degw[t]);
        int begin = pbase + prp[t];
        for (int j = raw; j < pad; ++j) csr[begin + j] = make_int2(node, 0);
    }
}

// XWs[i,f] = bf16(dinv[i] * XW[i,f])  — scale+convert stream (8 elems/thread)
__global__ __launch_bounds__(256) void k_scale(const float* __restrict__ XW,
                                               const float* __restrict__ dinv,
                                               unsigned short* __restrict__ XWs) {
    int g = blockIdx.x * 256 + threadIdx.x;
    int base = g * 8;
    if (base >= N_NODES * 64) return;
    float d = dinv[base >> 6];
    float4 v0 = *reinterpret_cast<const float4*>(XW + base);
    float4 v1 = *reinterpret_cast<const float4*>(XW + base + 4);
    usv8 r;
    r.s0 = f2bf(d * v0.x); r.s1 = f2bf(d * v0.y);
    r.s2 = f2bf(d * v0.z); r.s3 = f2bf(d * v0.w);
    r.s4 = f2bf(d * v1.x); r.s5 = f2bf(d * v1.y);
    r.s6 = f2bf(d * v1.z); r.s7 = f2bf(d * v1.w);
    *reinterpret_cast<usv8*>(XWs + base) = r;
}

// ---------------- dense compute ----------------

// gemm2: Y = X @ W with epilogue  XWs[gr,:] = bf16(dinv[gr] * Y[gr,:])
__global__ __launch_bounds__(256) void k_gemm64s(const float* __restrict__ X,
                                                 const float* __restrict__ W,
                                                 const float* __restrict__ dinv,
                                                 unsigned short* __restrict__ XWs) {
    __shared__ float sX[64][65];
    __shared__ float sW[64][65];
    int t = threadIdx.x;
    int rb = blockIdx.x * 64;
#pragma unroll
    for (int i = 0; i < 16; ++i) {
        int idx = t + i * 256;
        int r = idx >> 6, c = idx & 63;
        sW[r][c] = W[idx];
        int gr = rb + r;
        sX[r][c] = (gr < N_NODES) ? X[(size_t)gr * 64 + c] : 0.0f;
    }
    __syncthreads();
    int tr = (t >> 4) * 4;
    int tc = (t & 15) * 4;
    float acc[4][4] = {{0.f}};
#pragma unroll 8
    for (int k = 0; k < 64; ++k) {
        float xv[4], wv[4];
#pragma unroll
        for (int i = 0; i < 4; ++i) xv[i] = sX[tr + i][k];
#pragma unroll
        for (int j = 0; j < 4; ++j) wv[j] = sW[k][tc + j];
#pragma unroll
        for (int i = 0; i < 4; ++i)
#pragma unroll
            for (int j = 0; j < 4; ++j) acc[i][j] = fmaf(xv[i], wv[j], acc[i][j]);
    }
#pragma unroll
    for (int i = 0; i < 4; ++i) {
        int gr = rb + tr + i;
        if (gr < N_NODES) {
            float d = dinv[gr];
            ushort4 v;
            v.x = f2bf(d * acc[i][0]); v.y = f2bf(d * acc[i][1]);
            v.z = f2bf(d * acc[i][2]); v.w = f2bf(d * acc[i][3]);
            *reinterpret_cast<ushort4*>(&XWs[((unsigned)gr << 6) + tc]) = v;
        }
    }
}

// one wave per node, lane = feature. CSR path fully scalarized (s_load via K$).
// MODE 0: OUT[i,f] = relu(di*(selfs+esum) + bias)          (f32 row out)
// MODE 1: h = relu(...); OUT[i] = di * dot(h, W3)          (scalar xw3s out)
template <int MODE>
__global__ __launch_bounds__(256) void k_agg64(const unsigned short* __restrict__ XWs,
                                               const int* __restrict__ csr_i,
                                               const int2* __restrict__ rowinfo,
                                               const float* __restrict__ dinv,
                                               const float* __restrict__ bias,
                                               float* __restrict__ OUT,
                                               const float* __restrict__ W3) {
    int wid0 = (blockIdx.x * 256 + threadIdx.x) >> 6;
    if (wid0 >= N_NODES) return;                     // wave-uniform exit
    int wid = __builtin_amdgcn_readfirstlane(wid0);  // explicit SGPR
    unsigned f = threadIdx.x & 63;
    float di = dinv[wid];                            // scalar load
    float selfs = bf2f(XWs[((unsigned)wid << 6) + f]);
    int2 ri = rowinfo[wid];                          // scalar load
    int rbase = __builtin_amdgcn_readfirstlane(ri.x);
    int nb    = __builtin_amdgcn_readfirstlane(ri.y);
    const int* pc = csr_i + ((size_t)rbase * 2);     // uniform pointer
    float a[8] = {0.f, 0.f, 0.f, 0.f, 0.f, 0.f, 0.f, 0.f};
    for (int it = 0; it < nb; ++it, pc += 16) {
        int s0 = pc[0],  w0 = pc[1],  s1 = pc[2],  w1 = pc[3];
        int s2 = pc[4],  w2 = pc[5],  s3 = pc[6],  w3 = pc[7];
        int s4 = pc[8],  w4 = pc[9],  s5 = pc[10], w5 = pc[11];
        int s6 = pc[12], w6 = pc[13], s7 = pc[14], w7 = pc[15];
        float r0 = bf2f(XWs[((unsigned)s0 << 6) + f]);
        float r1 = bf2f(XWs[((unsigned)s1 << 6) + f]);
        float r2 = bf2f(XWs[((unsigned)s2 << 6) + f]);
        float r3 = bf2f(XWs[((unsigned)s3 << 6) + f]);
        float r4 = bf2f(XWs[((unsigned)s4 << 6) + f]);
        float r5 = bf2f(XWs[((unsigned)s5 << 6) + f]);
        float r6 = bf2f(XWs[((unsigned)s6 << 6) + f]);
        float r7 = bf2f(XWs[((unsigned)s7 << 6) + f]);
        a[0] = fmaf(__int_as_float(w0), r0, a[0]);
        a[1] = fmaf(__int_as_float(w1), r1, a[1]);
        a[2] = fmaf(__int_as_float(w2), r2, a[2]);
        a[3] = fmaf(__int_as_float(w3), r3, a[3]);
        a[4] = fmaf(__int_as_float(w4), r4, a[4]);
        a[5] = fmaf(__int_as_float(w5), r5, a[5]);
        a[6] = fmaf(__int_as_float(w6), r6, a[6]);
        a[7] = fmaf(__int_as_float(w7), r7, a[7]);
    }
    float esum = ((a[0] + a[1]) + (a[2] + a[3])) + ((a[4] + a[5]) + (a[6] + a[7]));
    float acc = di * (selfs + esum) + bias[f];
    acc = fmaxf(acc, 0.0f);
    if (MODE == 0) {
        OUT[((unsigned)wid << 6) + f] = acc;
    } else {
        float v = acc * W3[f];
#pragma unroll
        for (int off = 32; off > 0; off >>= 1) v += __shfl_down(v, off, 64);
        if (f == 0) OUT[wid] = di * v;          // store xw3s = dinv * xw3
    }
}

// out[i] = b3 + di*(xw3s[i] + sum_e w_e*xw3s[src_e])   (raw w, scaled table)
__global__ __launch_bounds__(256) void k_agg_scalar(const float* __restrict__ xw3s,
                                                    const int2* __restrict__ csr,
                                                    const int2* __restrict__ rowinfo,
                                                    const float* __restrict__ dinv,
                                                    const float* __restrict__ b3,
                                                    float* __restrict__ out) {
    int i = blockIdx.x * 256 + threadIdx.x;
    if (i >= N_NODES) return;
    float di = dinv[i];
    int2 ri = rowinfo[i];
    const iv4* p = reinterpret_cast<const iv4*>(csr + ri.x);
    int nb = ri.y;
    float a0 = 0.f, a1 = 0.f, a2 = 0.f, a3 = 0.f;
    for (int it = 0; it < nb; ++it, p += 4) {
        iv4 q0 = __builtin_nontemporal_load(p);
        iv4 q1 = __builtin_nontemporal_load(p + 1);
        iv4 q2 = __builtin_nontemporal_load(p + 2);
        iv4 q3 = __builtin_nontemporal_load(p + 3);
        a0 = fmaf(__int_as_float(q0.y), xw3s[q0.x], a0);
        a1 = fmaf(__int_as_float(q0.w), xw3s[q0.z], a1);
        a2 = fmaf(__int_as_float(q1.y), xw3s[q1.x], a2);
        a3 = fmaf(__int_as_float(q1.w), xw3s[q1.z], a3);
        a0 = fmaf(__int_as_float(q2.y), xw3s[q2.x], a0);
        a1 = fmaf(__int_as_float(q2.w), xw3s[q2.z], a1);
        a2 = fmaf(__int_as_float(q3.y), xw3s[q3.x], a2);
        a3 = fmaf(__int_as_float(q3.w), xw3s[q3.z], a3);
    }
    out[i] = di * (xw3s[i] + (a0 + a1) + (a2 + a3)) + b3[0];
}

// ---------------- launch ----------------

extern "C" void kernel_launch(void* const* d_in, const int* in_sizes, int n_in,
                              void* d_out, int out_size, void* d_ws, size_t ws_size,
                              hipStream_t stream) {
    const float* x  = (const float*)d_in[0];
    const int*   ei = (const int*)d_in[1];     // int32 per harness contract
    const float* ea = (const float*)d_in[2];
    const float* W1 = (const float*)d_in[3];
    const float* b1 = (const float*)d_in[4];
    const float* W2 = (const float*)d_in[5];
    const float* b2 = (const float*)d_in[6];
    const float* W3 = (const float*)d_in[7];
    const float* b3 = (const float*)d_in[8];
    float* out = (float*)d_out;
    const int* srcarr = ei;
    const int* dstarr = ei + N_EDGES;

    char* ws = (char*)d_ws;
    size_t off = 0;
    auto alloc = [&](size_t bytes) -> void* {
        void* p = ws + off;
        off = (off + bytes + 255) & ~(size_t)255;
        return p;
    };
    float* dinv     = (float*)alloc((size_t)N_NODES * 4);
    int2*  rowinfo  = (int2*) alloc((size_t)N_NODES * 8);
    int*   gcursor  = (int*)  alloc(NBUCKET * 4);
    float* xw3s     = (float*)alloc((size_t)N_NODES * 4);
    // bsw (14.5 MB; dead after P2) shares its region with XWs1 (12.8 MB)
    void*  region   = alloc((size_t)NBUCKET * BSW_CAP * 8);
    uint2*          bsw  = (uint2*)region;
    unsigned short* XWs1 = (unsigned short*)region;
    int2*  csr      = (int2*) alloc((size_t)NBUCKET * CSR_CAP * 8);
    float* bufA     = (float*)alloc((size_t)N_NODES * 64 * 4);   // gemm1 out; reused as XWs2
    float* bufB     = (float*)alloc((size_t)N_NODES * 64 * 4);
    unsigned short* XWs2 = (unsigned short*)bufA;  // bufA dead after k_scale reads it

    const int nbW = N_NODES / 4;             // 25000
    const int nbN = (N_NODES + 255) / 256;   // 391
    const int nbS = (N_NODES * 64 / 8 + 255) / 256;   // 3125 scale blocks

    k_init<<<1, 256, 0, stream>>>(gcursor);
    k_p1gemm<<<NB_P1 + NBG, 256, 0, stream>>>(dstarr, srcarr, ea, gcursor,
                                              bsw, x, W1, bufA);
    k_p2<<<NBUCKET, 1024, 0, stream>>>(bsw, gcursor, rowinfo, csr, dinv);
    k_scale<<<nbS, 256, 0, stream>>>(bufA, dinv, XWs1);   // overwrites bsw region

    k_agg64<0><<<nbW, 256, 0, stream>>>(XWs1, (const int*)csr, rowinfo, dinv, b1, bufB, nullptr);
    k_gemm64s<<<NBG, 256, 0, stream>>>(bufB, W2, dinv, XWs2);   // overwrites bufA
    k_agg64<1><<<nbW, 256, 0, stream>>>(XWs2, (const int*)csr, rowinfo, dinv, b2, xw3s, W3);
    k_agg_scalar<<<nbN, 256, 0, stream>>>(xw3s, csr, rowinfo, dinv, b3, out);
}